// Round 9
// baseline (7969.372 us; speedup 1.0000x reference)
//
#include <hip/hip_runtime.h>
#include <math.h>
#include <stdint.h>

#define DIMM 512
#define MATF ((size_t)DIMM * DIMM)       // 262144
#define PLANE 262144                     // hi -> lo plane offset (ushorts)
#define SLOT_USH (2 * 262144)            // pair slot per batch (ushorts) = 1 MiB

typedef __attribute__((ext_vector_type(8))) short short8v;
typedef __attribute__((ext_vector_type(8))) unsigned short ushort8v;
typedef __attribute__((ext_vector_type(4))) float f32x4;

#define MODE_SQ 1

__device__ __forceinline__ unsigned short bf16_rne(float f) {
    unsigned u = __builtin_bit_cast(unsigned, f);
    u += 0x7FFFu + ((u >> 16) & 1u);
    return (unsigned short)(u >> 16);
}
__device__ __forceinline__ float bf16_to_f(unsigned short h) {
    unsigned u = ((unsigned)h) << 16;
    return __builtin_bit_cast(float, u);
}
__device__ __forceinline__ float sgn_sqrt(float tv)
{
    float r = sqrtf(fabsf(tv) + 1e-5f);
    return tv > 0.f ? r : (tv < 0.f ? -r : 0.f);
}

// fp32x8 -> trunc hi/lo bf16x8 pair
__device__ __forceinline__ void cvt8(const float4 f0, const float4 f1,
                                     ushort8v& h, ushort8v& l)
{
    float v0 = f0.x, v1 = f0.y, v2 = f0.z, v3 = f0.w;
    float v4 = f1.x, v5 = f1.y, v6 = f1.z, v7 = f1.w;
#define CV1(IDX, VV) do { \
    unsigned u = __builtin_bit_cast(unsigned, VV); \
    h[IDX] = (unsigned short)(u >> 16); \
    float r = (VV) - __builtin_bit_cast(float, u & 0xFFFF0000u); \
    l[IDX] = (unsigned short)(__builtin_bit_cast(unsigned, r) >> 16); \
  } while (0)
    CV1(0, v0); CV1(1, v1); CV1(2, v2); CV1(3, v3);
    CV1(4, v4); CV1(5, v5); CV1(6, v6); CV1(7, v7);
#undef CV1
}

// ---------------------------------------------------------------------------
// NS GEMM — rolled K-loop (runtime geometry), reg-staged prefetch, 32 KiB LDS
// (4 planes x 128 rows x 32 ushorts, XOR-chunk involution: chunk slot =
// g ^ ((row>>1)&3) on both ds_write and ds_read — round-7-verified) =>
// 5 blocks/CU so the 1280-block s1 launch fits in ONE occupancy wave.
// C_pair = f(1.5*A - 0.5*(A @ B^T-as-cols)); symmetric 10-tile; mirror via
// two 64-row LDS half-pass transposes (pitch 70). XCD-aware remap.
// mode MODE_SQ: epilogue v = sgn_sqrt(v * sqrt(norm[bz]))   (it9 fusion)
// ---------------------------------------------------------------------------
__global__ __launch_bounds__(256, 5) void ns_gemm(
    const unsigned short* __restrict__ A0, const unsigned short* __restrict__ A1,
    const unsigned short* __restrict__ Bb,
    unsigned short* __restrict__ C0, unsigned short* __restrict__ C1,
    int lda, long aslot, int aplane,
    int ldb, long bslot, int bplane,
    int K, int mode, const float* __restrict__ norm, int nz)
{
    __shared__ __align__(16) unsigned short sm[16384];   // 32 KiB exactly

    // ---- XCD-aware remap: batch-contiguous per XCD
    const int nwg = gridDim.x;
    const int chunk = nwg >> 3;                   // nwg % 8 == 0
    const int bid = blockIdx.x;
    const int wu = (bid & 7) * chunk + (bid >> 3);
    const int per_batch = nz * 10;
    const int bz = wu / per_batch;
    const int rr = wu - bz * per_batch;
    const int z  = rr / 10;
    const int tile = rr - z * 10;
    int ti, tj;
    if (tile < 4)      { ti = 0; tj = tile; }
    else if (tile < 7) { ti = 1; tj = tile - 3; }
    else if (tile < 9) { ti = 2; tj = tile - 5; }
    else               { ti = 3; tj = 3; }

    const unsigned short* A  = (z ? A1 : A0) + (size_t)bz * aslot;
    const unsigned short* Bp = Bb + (size_t)bz * bslot;
    unsigned short* C = (z ? C1 : C0) + (size_t)bz * SLOT_USH;

    float sq = 0.f;
    if (mode) sq = sqrtf(norm[bz]);

    const int m0 = ti * 128;
    const int n0 = tj * 128;

    const int t = threadIdx.x;
    const int l = t & 63;
    const int w = t >> 6;
    const int wr = w >> 1, wc = w & 1;
    const int lr = l & 15;
    // swizzled k-chunk read offset (ushorts): logical chunk l>>4 at row group
    const int sc = (((l >> 4) ^ ((l >> 1) & 3)) << 3);

    // staging: thread covers row sr, global chunks {2sh, 2sh+1}; XOR'd slots
    const int sr = t >> 1, sh = t & 1;
    const int swz = (sr >> 1) & 3;
    const int slot0 = ((((sh << 1) | 0) ^ swz) << 3);
    const int slot1 = ((((sh << 1) | 1) ^ swz) << 3);
    const int wbase = sr * 32;
    const unsigned short* pA = A  + (size_t)(m0 + sr) * lda + sh * 16;
    const unsigned short* pB = Bp + (size_t)(n0 + sr) * ldb + sh * 16;

    f32x4 acc[4][4] = {};

    ushort8v a0, a1, a2, a3, b0, b1, b2, b3;
#define LOADALL(OFF) do { \
    a0 = *(const ushort8v*)(pA + (OFF));              a1 = *(const ushort8v*)(pA + (OFF) + 8); \
    a2 = *(const ushort8v*)(pA + aplane + (OFF));     a3 = *(const ushort8v*)(pA + aplane + (OFF) + 8); \
    b0 = *(const ushort8v*)(pB + (OFF));              b1 = *(const ushort8v*)(pB + (OFF) + 8); \
    b2 = *(const ushort8v*)(pB + bplane + (OFF));     b3 = *(const ushort8v*)(pB + bplane + (OFF) + 8); \
  } while (0)

    LOADALL(0);
    const int nsteps = K >> 5;
    for (int s = 0; s < nsteps; ++s) {
        __syncthreads();
        *(ushort8v*)&sm[        wbase + slot0] = a0; *(ushort8v*)&sm[        wbase + slot1] = a1;
        *(ushort8v*)&sm[ 4096 + wbase + slot0] = a2; *(ushort8v*)&sm[ 4096 + wbase + slot1] = a3;
        *(ushort8v*)&sm[ 8192 + wbase + slot0] = b0; *(ushort8v*)&sm[ 8192 + wbase + slot1] = b1;
        *(ushort8v*)&sm[12288 + wbase + slot0] = b2; *(ushort8v*)&sm[12288 + wbase + slot1] = b3;
        __syncthreads();
        if (s + 1 < nsteps) LOADALL((s + 1) * 32);

        short8v ah[4], al[4], bh[4], bl[4];
#pragma unroll
        for (int f = 0; f < 4; ++f) {
            const int ra = ((wr * 64 + f * 16 + lr) << 5) + sc;
            const int rb = ((wc * 64 + f * 16 + lr) << 5) + sc;
            ah[f] = *(const short8v*)(&sm[ra]);
            al[f] = *(const short8v*)(&sm[4096 + ra]);
            bh[f] = *(const short8v*)(&sm[8192 + rb]);
            bl[f] = *(const short8v*)(&sm[12288 + rb]);
        }
#pragma unroll
        for (int fm = 0; fm < 4; ++fm)
#pragma unroll
            for (int fn = 0; fn < 4; ++fn) {
                acc[fm][fn] = __builtin_amdgcn_mfma_f32_16x16x32_bf16(ah[fm], bh[fn], acc[fm][fn], 0, 0, 0);
                acc[fm][fn] = __builtin_amdgcn_mfma_f32_16x16x32_bf16(ah[fm], bl[fn], acc[fm][fn], 0, 0, 0);
                acc[fm][fn] = __builtin_amdgcn_mfma_f32_16x16x32_bf16(al[fm], bh[fn], acc[fm][fn], 0, 0, 0);
            }
    }
#undef LOADALL

    // epilogue: v = 1.5*A - 0.5*acc (+optional ssqrt); write upper tile
    // C/D layout: col = lane&15, row = (lane>>4)*4 + reg  [m89-verified]
#pragma unroll
    for (int fm = 0; fm < 4; ++fm) {
#pragma unroll
        for (int j = 0; j < 4; ++j) {
            const int row = m0 + wr * 64 + fm * 16 + (l >> 4) * 4 + j;
            const unsigned short* arow = A + (size_t)row * lda;
            const size_t crow = (size_t)row * 512;
#pragma unroll
            for (int fn = 0; fn < 4; ++fn) {
                const int col = n0 + wc * 64 + fn * 16 + lr;
                float pv = bf16_to_f(arow[col]) + bf16_to_f(arow[aplane + col]);
                float v = 1.5f * pv - 0.5f * acc[fm][fn][j];
                if (mode & MODE_SQ) v = sgn_sqrt(v * sq);
                acc[fm][fn][j] = v;
                unsigned short hh = bf16_rne(v);
                C[crow + col] = hh;
                C[crow + col + PLANE] = bf16_rne(v - bf16_to_f(hh));
            }
        }
    }

    // mirrored (lower-triangle) tile: two 64-row half-pass LDS transposes
    if (ti != tj) {
        const int TP = 70;                        // pitch (ushorts), bank-spread
        unsigned short* smT = sm;                 // 128*70 = 8960 ushorts, fits
        const int cst = wc * 64 + lr;             // transposed-row (= orig col)
        const int r4  = (l >> 4) * 4;             // row-offset within half
        const int rc2 = t >> 1;                   // readout row 0..127
        const int chh = t & 1;                    // readout 32-col half
        __syncthreads();
#pragma unroll
        for (int pl = 0; pl < 2; ++pl) {
#pragma unroll
            for (int h = 0; h < 2; ++h) {
                if (wr == h) {
#pragma unroll
                    for (int fm = 0; fm < 4; ++fm) {
#pragma unroll
                        for (int fn = 0; fn < 4; ++fn) {
                            ushort4 q;
                            {
                                float v0 = acc[fm][fn][0], v1 = acc[fm][fn][1];
                                float v2 = acc[fm][fn][2], v3 = acc[fm][fn][3];
                                unsigned short h0 = bf16_rne(v0), h1 = bf16_rne(v1);
                                unsigned short h2 = bf16_rne(v2), h3 = bf16_rne(v3);
                                if (pl == 0) { q.x = h0; q.y = h1; q.z = h2; q.w = h3; }
                                else {
                                    q.x = bf16_rne(v0 - bf16_to_f(h0));
                                    q.y = bf16_rne(v1 - bf16_to_f(h1));
                                    q.z = bf16_rne(v2 - bf16_to_f(h2));
                                    q.w = bf16_rne(v3 - bf16_to_f(h3));
                                }
                            }
                            *(ushort4*)&smT[(cst + fn * 16) * TP + r4 + fm * 16] = q;
                        }
                    }
                }
                __syncthreads();
                {
                    unsigned short* dst = C + (size_t)(n0 + rc2) * 512 + m0 + h * 64
                                            + chh * 32 + (pl ? PLANE : 0);
                    const unsigned short* srcp = &smT[rc2 * TP + chh * 32];
#pragma unroll
                    for (int k = 0; k < 8; ++k)
                        *(ushort4*)(dst + k * 4) = *(const ushort4*)(srcp + k * 4);
                }
                __syncthreads();
            }
        }
    }
}

// ---------------------------------------------------------------------------
// Gram: C_pair = (X X^T)/784, symmetric 10-tile + mirror, K=784 (25 steps).
// Reg-staged prefetch; fp32->pair conversion AFTER the MFMA block.
// ---------------------------------------------------------------------------
__global__ __launch_bounds__(256) void gram_direct(const float* __restrict__ X,
                                                   unsigned short* __restrict__ C0,
                                                   float alpha)
{
    __shared__ __align__(16) unsigned short sm[16896];

    const int nwg = gridDim.x;
    const int chunk = nwg >> 3;
    const int wu = (blockIdx.x & 7) * chunk + (blockIdx.x >> 3);
    const int bz = wu / 10, tile = wu - bz * 10;
    int ti, tj;
    if (tile < 4)      { ti = 0; tj = tile; }
    else if (tile < 7) { ti = 1; tj = tile - 3; }
    else if (tile < 9) { ti = 2; tj = tile - 5; }
    else               { ti = 3; tj = 3; }
    const int m0 = ti * 128, n0 = tj * 128;
    unsigned short* C = C0 + (size_t)bz * SLOT_USH;

    const int t = threadIdx.x;
    const int l = t & 63;
    const int w = t >> 6;
    const int wr = w >> 1, wc = w & 1;
    const int lr = l & 15;
    const int sc = (((l >> 4) ^ ((l >> 1) & 3)) << 3);

    const int sr = t >> 1, sh = t & 1;
    const int swz = (sr >> 1) & 3;
    const int slot0 = (((sh << 1) | 0) ^ swz) << 3;
    const int slot1 = (((sh << 1) | 1) ^ swz) << 3;
    const int wbase = sr * 32;

    const float* pXa = X + ((size_t)bz * 512 + m0 + sr) * 784 + sh * 16;
    const float* pXb = X + ((size_t)bz * 512 + n0 + sr) * 784 + sh * 16;

    f32x4 acc[4][4] = {};

    float4 xa0, xa1, xa2, xa3, xb0, xb1, xb2, xb3;
    ushort8v ah0, ah1, al0, al1, bh0, bh1, bl0, bl1;

#define GLD(OFF) do { \
    if ((OFF) + sh * 16 < 784) { \
        xa0 = *(const float4*)(pXa + (OFF));      xa1 = *(const float4*)(pXa + (OFF) + 4); \
        xa2 = *(const float4*)(pXa + (OFF) + 8);  xa3 = *(const float4*)(pXa + (OFF) + 12); \
        xb0 = *(const float4*)(pXb + (OFF));      xb1 = *(const float4*)(pXb + (OFF) + 4); \
        xb2 = *(const float4*)(pXb + (OFF) + 8);  xb3 = *(const float4*)(pXb + (OFF) + 12); \
    } else { \
        xa0 = xa1 = xa2 = xa3 = make_float4(0.f, 0.f, 0.f, 0.f); \
        xb0 = xb1 = xb2 = xb3 = make_float4(0.f, 0.f, 0.f, 0.f); \
    } } while (0)

#define CONVALL() do { \
    cvt8(xa0, xa1, ah0, al0); cvt8(xa2, xa3, ah1, al1); \
    cvt8(xb0, xb1, bh0, bl0); cvt8(xb2, xb3, bh1, bl1); \
  } while (0)

    GLD(0);
    CONVALL();
    for (int s = 0; s < 25; ++s) {
        __syncthreads();
        *(ushort8v*)&sm[        wbase + slot0] = ah0;  *(ushort8v*)&sm[        wbase + slot1] = ah1;
        *(ushort8v*)&sm[ 4096 + wbase + slot0] = al0;  *(ushort8v*)&sm[ 4096 + wbase + slot1] = al1;
        *(ushort8v*)&sm[ 8192 + wbase + slot0] = bh0;  *(ushort8v*)&sm[ 8192 + wbase + slot1] = bh1;
        *(ushort8v*)&sm[12288 + wbase + slot0] = bl0;  *(ushort8v*)&sm[12288 + wbase + slot1] = bl1;
        __syncthreads();
        if (s + 1 < 25) GLD((s + 1) * 32);

        short8v ah[4], al[4], bh[4], bl[4];
#pragma unroll
        for (int f = 0; f < 4; ++f) {
            const int ra = ((wr * 64 + f * 16 + lr) << 5) + sc;
            const int rb = ((wc * 64 + f * 16 + lr) << 5) + sc;
            ah[f] = *(const short8v*)(&sm[ra]);
            al[f] = *(const short8v*)(&sm[4096 + ra]);
            bh[f] = *(const short8v*)(&sm[8192 + rb]);
            bl[f] = *(const short8v*)(&sm[12288 + rb]);
        }
#pragma unroll
        for (int fm = 0; fm < 4; ++fm)
#pragma unroll
            for (int fn = 0; fn < 4; ++fn) {
                acc[fm][fn] = __builtin_amdgcn_mfma_f32_16x16x32_bf16(ah[fm], bh[fn], acc[fm][fn], 0, 0, 0);
                acc[fm][fn] = __builtin_amdgcn_mfma_f32_16x16x32_bf16(ah[fm], bl[fn], acc[fm][fn], 0, 0, 0);
                acc[fm][fn] = __builtin_amdgcn_mfma_f32_16x16x32_bf16(al[fm], bh[fn], acc[fm][fn], 0, 0, 0);
            }
        if (s + 1 < 25) CONVALL();
    }
#undef GLD
#undef CONVALL

#pragma unroll
    for (int fm = 0; fm < 4; ++fm) {
#pragma unroll
        for (int j = 0; j < 4; ++j) {
            const int row = m0 + wr * 64 + fm * 16 + (l >> 4) * 4 + j;
            const size_t crow = (size_t)row * 512;
#pragma unroll
            for (int fn = 0; fn < 4; ++fn) {
                const int col = n0 + wc * 64 + fn * 16 + lr;
                float v = acc[fm][fn][j] * alpha;
                acc[fm][fn][j] = v;
                unsigned short hh = bf16_rne(v);
                C[crow + col] = hh;
                C[crow + col + PLANE] = bf16_rne(v - bf16_to_f(hh));
            }
        }
    }

    if (ti != tj) {
        const int TP = 70;
        unsigned short* smT = sm;
        const int cst = wc * 64 + lr;
        const int r4  = (l >> 4) * 4;
        const int rc2 = t >> 1;
        const int chh = t & 1;
        __syncthreads();
#pragma unroll
        for (int pl = 0; pl < 2; ++pl) {
#pragma unroll
            for (int h = 0; h < 2; ++h) {
                if (wr == h) {
#pragma unroll
                    for (int fm = 0; fm < 4; ++fm) {
#pragma unroll
                        for (int fn = 0; fn < 4; ++fn) {
                            ushort4 q;
                            {
                                float v0 = acc[fm][fn][0], v1 = acc[fm][fn][1];
                                float v2 = acc[fm][fn][2], v3 = acc[fm][fn][3];
                                unsigned short h0 = bf16_rne(v0), h1 = bf16_rne(v1);
                                unsigned short h2 = bf16_rne(v2), h3 = bf16_rne(v3);
                                if (pl == 0) { q.x = h0; q.y = h1; q.z = h2; q.w = h3; }
                                else {
                                    q.x = bf16_rne(v0 - bf16_to_f(h0));
                                    q.y = bf16_rne(v1 - bf16_to_f(h1));
                                    q.z = bf16_rne(v2 - bf16_to_f(h2));
                                    q.w = bf16_rne(v3 - bf16_to_f(h3));
                                }
                            }
                            *(ushort4*)&smT[(cst + fn * 16) * TP + r4 + fm * 16] = q;
                        }
                    }
                }
                __syncthreads();
                {
                    unsigned short* dst = C + (size_t)(n0 + rc2) * 512 + m0 + h * 64
                                            + chh * 32 + (pl ? PLANE : 0);
                    const unsigned short* srcp = &smT[rc2 * TP + chh * 32];
#pragma unroll
                    for (int k = 0; k < 8; ++k)
                        *(ushort4*)(dst + k * 4) = *(const ushort4*)(srcp + k * 4);
                }
                __syncthreads();
            }
        }
    }
}

// ---------------------------------------------------------------------------
// Y0_pair = A_pair / norm[b]
// ---------------------------------------------------------------------------
__global__ __launch_bounds__(256) void init_pair(const unsigned short* __restrict__ A,
                                                 unsigned short* __restrict__ Y,
                                                 const float* __restrict__ norm)
{
    const int total = 64 * 32768;
    for (int g = blockIdx.x * 256 + threadIdx.x; g < total; g += gridDim.x * 256) {
        const int b = g >> 15;
        const int off = (g & 32767) * 8;
        const float rn = 1.0f / norm[b];
        const unsigned short* ah = A + (size_t)b * SLOT_USH + off;
        ushort8v h = *(const ushort8v*)ah;
        ushort8v lo = *(const ushort8v*)(ah + PLANE);
        ushort8v oh, ol;
#pragma unroll
        for (int j = 0; j < 8; ++j) {
            float v = (bf16_to_f(h[j]) + bf16_to_f(lo[j])) * rn;
            unsigned short hh = bf16_rne(v);
            oh[j] = hh;
            ol[j] = bf16_rne(v - bf16_to_f(hh));
        }
        unsigned short* y = Y + (size_t)b * SLOT_USH + off;
        *(ushort8v*)y = oh;
        *(ushort8v*)(y + PLANE) = ol;
    }
}

// ---------------------------------------------------------------------------
// Frobenius norm, two-stage: 512-block partial + finish
// ---------------------------------------------------------------------------
__global__ __launch_bounds__(256) void frob_part(const unsigned short* __restrict__ P,
                                                 float* __restrict__ pp)
{
    const int b = blockIdx.x >> 3, sg = blockIdx.x & 7;
    const unsigned short* p = P + (size_t)b * SLOT_USH + sg * 32768;
    float s = 0.f;
    for (int i = threadIdx.x * 8; i < 32768; i += 2048) {
        ushort8v h = *(const ushort8v*)(p + i);
        ushort8v lo = *(const ushort8v*)(p + i + PLANE);
#pragma unroll
        for (int j = 0; j < 8; ++j) {
            float v = bf16_to_f(h[j]) + bf16_to_f(lo[j]);
            s += v * v;
        }
    }
    __shared__ float red[256];
    red[threadIdx.x] = s;
    __syncthreads();
    for (int wd = 128; wd > 0; wd >>= 1) {
        if (threadIdx.x < wd) red[threadIdx.x] += red[threadIdx.x + wd];
        __syncthreads();
    }
    if (threadIdx.x == 0) pp[blockIdx.x] = red[0];
}

__global__ __launch_bounds__(64) void frob_fin(const float* __restrict__ pp,
                                               float* __restrict__ out)
{
    const int b = threadIdx.x;
    float s = 0.f;
#pragma unroll
    for (int i = 0; i < 8; ++i) s += pp[b * 8 + i];
    out[b] = sqrtf(s);
}

// ---------------------------------------------------------------------------
// FC via MFMA, k-split: grid 256 (128 sp x 2 nt)
// ---------------------------------------------------------------------------
__global__ __launch_bounds__(256) void fc_mfma(
    const unsigned short* __restrict__ Vp, const float* __restrict__ Wfc,
    float* __restrict__ part)
{
    __shared__ unsigned short sm2[15360];
    const int AH = 0, AL = 2560, BH = 5120, BL = 10240;

    const int sp = blockIdx.x >> 1;
    const int nt = blockIdx.x & 1;
    const int kbase = sp * 2048;
    const int n0 = nt * 128;

    const int t = threadIdx.x;
    const int l = t & 63;
    const int w = t >> 6;
    const int wr = w >> 1, wc = w & 1;
    const int lr = l & 15, lc16 = (l >> 4) * 8;

    const int sr = t >> 1, sh = t & 1;
    const unsigned short* gA = Vp + (size_t)sr * SLOT_USH + kbase + sh * 16;
    const int wrow = n0 + sr;
    const bool wv = wrow < 200;
    const float* gB = Wfc + (size_t)wrow * 262144 + kbase + sh * 16;

    unsigned short* dAh = &sm2[AH + sr * 40 + sh * 16];
    unsigned short* dAl = &sm2[AL + sr * 40 + sh * 16];
    unsigned short* dBh = &sm2[BH + sr * 40 + sh * 16];
    unsigned short* dBl = &sm2[BL + sr * 40 + sh * 16];

    f32x4 acc[2][4] = {};

    ushort8v va0, va1, vl0, vl1;
    float4 wf0, wf1, wf2, wf3;
#define FLOAD(OFF) do { \
    if (t < 128) { \
        va0 = *(const ushort8v*)(gA + (OFF));         va1 = *(const ushort8v*)(gA + (OFF) + 8); \
        vl0 = *(const ushort8v*)(gA + PLANE + (OFF)); vl1 = *(const ushort8v*)(gA + PLANE + (OFF) + 8); \
    } \
    if (wv) { \
        wf0 = *(const float4*)(gB + (OFF));      wf1 = *(const float4*)(gB + (OFF) + 4); \
        wf2 = *(const float4*)(gB + (OFF) + 8);  wf3 = *(const float4*)(gB + (OFF) + 12); \
    } else { \
        wf0 = wf1 = wf2 = wf3 = make_float4(0.f, 0.f, 0.f, 0.f); \
    } \
  } while (0)

#define WCONV(F4, Q) do { \
    ushort4 h4, l4; \
    unsigned ux = __builtin_bit_cast(unsigned, (F4).x); \
    unsigned uy = __builtin_bit_cast(unsigned, (F4).y); \
    unsigned uz = __builtin_bit_cast(unsigned, (F4).z); \
    unsigned uw = __builtin_bit_cast(unsigned, (F4).w); \
    h4.x = (unsigned short)(ux >> 16); h4.y = (unsigned short)(uy >> 16); \
    h4.z = (unsigned short)(uz >> 16); h4.w = (unsigned short)(uw >> 16); \
    l4.x = (unsigned short)(__builtin_bit_cast(unsigned, (F4).x - __builtin_bit_cast(float, ux & 0xFFFF0000u)) >> 16); \
    l4.y = (unsigned short)(__builtin_bit_cast(unsigned, (F4).y - __builtin_bit_cast(float, uy & 0xFFFF0000u)) >> 16); \
    l4.z = (unsigned short)(__builtin_bit_cast(unsigned, (F4).z - __builtin_bit_cast(float, uz & 0xFFFF0000u)) >> 16); \
    l4.w = (unsigned short)(__builtin_bit_cast(unsigned, (F4).w - __builtin_bit_cast(float, uw & 0xFFFF0000u)) >> 16); \
    *(ushort4*)(dBh + (Q) * 4) = h4; \
    *(ushort4*)(dBl + (Q) * 4) = l4; \
  } while (0)

    FLOAD(0);
    for (int s = 0; s < 64; ++s) {
        __syncthreads();
        if (t < 128) {
            *(ushort8v*)(dAh) = va0; *(ushort8v*)(dAh + 8) = va1;
            *(ushort8v*)(dAl) = vl0; *(ushort8v*)(dAl + 8) = vl1;
        }
        WCONV(wf0, 0); WCONV(wf1, 1); WCONV(wf2, 2); WCONV(wf3, 3);
        __syncthreads();
        if (s + 1 < 64) FLOAD((s + 1) * 32);

        short8v ah[2], al2[2], bh[4], bl[4];
#pragma unroll
        for (int f = 0; f < 2; ++f) {
            const int ra = (wr * 32 + f * 16 + lr) * 40 + lc16;
            ah[f]  = *(const short8v*)(&sm2[AH + ra]);
            al2[f] = *(const short8v*)(&sm2[AL + ra]);
        }
#pragma unroll
        for (int f = 0; f < 4; ++f) {
            const int rb = (wc * 64 + f * 16 + lr) * 40 + lc16;
            bh[f] = *(const short8v*)(&sm2[BH + rb]);
            bl[f] = *(const short8v*)(&sm2[BL + rb]);
        }
#pragma unroll
        for (int fm = 0; fm < 2; ++fm)
#pragma unroll
            for (int fn = 0; fn < 4; ++fn) {
                acc[fm][fn] = __builtin_amdgcn_mfma_f32_16x16x32_bf16(ah[fm],  bh[fn], acc[fm][fn], 0, 0, 0);
                acc[fm][fn] = __builtin_amdgcn_mfma_f32_16x16x32_bf16(ah[fm],  bl[fn], acc[fm][fn], 0, 0, 0);
                acc[fm][fn] = __builtin_amdgcn_mfma_f32_16x16x32_bf16(al2[fm], bh[fn], acc[fm][fn], 0, 0, 0);
            }
    }
#undef FLOAD
#undef WCONV

    float* pb = part + (size_t)(sp * 2 + nt) * 64 * 128;
#pragma unroll
    for (int fm = 0; fm < 2; ++fm)
#pragma unroll
        for (int j = 0; j < 4; ++j) {
            const int row = wr * 32 + fm * 16 + (l >> 4) * 4 + j;
#pragma unroll
            for (int fn = 0; fn < 4; ++fn) {
                const int col = wc * 64 + fn * 16 + lr;
                pb[(size_t)row * 128 + col] = acc[fm][fn][j];
            }
        }
}

__global__ __launch_bounds__(256) void fc_reduce(
    const float* __restrict__ part, const float* __restrict__ n2,
    const float* __restrict__ bias, float* __restrict__ out)
{
    const int p = blockIdx.x * 256 + threadIdx.x;
    if (p >= 64 * 200) return;
    const int b = p / 200, o = p % 200;
    const int nt = o >> 7, n = o & 127;
    float s = 0.f;
    for (int c = 0; c < 128; ++c)
        s += part[((size_t)(c * 2 + nt) * 64 + b) * 128 + n];
    const float nb = fmaxf(n2[b], 1e-12f);
    out[p] = s / nb + bias[o];
}

// ---------------------------------------------------------------------------
extern "C" void kernel_launch(void* const* d_in, const int* in_sizes, int n_in,
                              void* d_out, int out_size, void* d_ws, size_t ws_size,
                              hipStream_t stream)
{
    const float* X    = (const float*)d_in[0];
    const float* Wfc  = (const float*)d_in[1];
    const float* bias = (const float*)d_in[2];
    float* out = (float*)d_out;

    float* norm  = (float*)d_ws;
    float* norm2 = norm + 64;
    float* fpart = norm2 + 64;                       // 512
    float* part  = fpart + 512;                      // 8 MiB
    unsigned short* region = (unsigned short*)(part + (size_t)256 * 64 * 128);

    unsigned short* P[4];
    for (int i = 0; i < 4; ++i) P[i] = region + (size_t)i * 64 * SLOT_USH;

    // A = X X^T / 784 -> P0; norm; Y0 = A/norm -> P1
    gram_direct<<<640, 256, 0, stream>>>(X, P[0], 1.0f / 784.0f);
    frob_part<<<512, 256, 0, stream>>>(P[0], fpart);
    frob_fin<<<1, 64, 0, stream>>>(fpart, norm);
    init_pair<<<1024, 256, 0, stream>>>(P[0], P[1], norm);

    // Newton-Schulz (M-form): T(M) = (3I - M)/2 folded into epilogue
    // it0a: Y1 = Y0*T(Y0) -> P2 ; it0b: M1 = Y1*T(Y0) -> P3
    ns_gemm<<<640, 256, 0, stream>>>(P[1], P[1], P[1], P[2], P[2],
        512, (long)SLOT_USH, PLANE, 512, (long)SLOT_USH, PLANE, 512, 0, norm, 1);
    ns_gemm<<<640, 256, 0, stream>>>(P[2], P[2], P[1], P[3], P[3],
        512, (long)SLOT_USH, PLANE, 512, (long)SLOT_USH, PLANE, 512, 0, norm, 1);

    unsigned short *Y = P[2], *M = P[3], *F0 = P[0], *F1 = P[1];
    for (int it = 1; it <= 8; ++it) {
        // s1 merged: z=0: U = M*T(M) -> F0 ; z=1: Ynew = Y*T(M) -> F1
        ns_gemm<<<1280, 256, 0, stream>>>(M, Y, M, F0, F1,
            512, (long)SLOT_USH, PLANE, 512, (long)SLOT_USH, PLANE, 512, 0, norm, 2);
        // s2: Mnew = U*T(M) -> old Y slot
        ns_gemm<<<640, 256, 0, stream>>>(F0, F0, M, Y, Y,
            512, (long)SLOT_USH, PLANE, 512, (long)SLOT_USH, PLANE, 512, 0, norm, 1);
        unsigned short* Mold = M;
        M = Y;        // Mnew in old Y slot
        Y = F1;       // Ynew
        F1 = Mold;    // Mold freed; F0 unchanged
    }
    // it9 + fused signed-sqrt: V = sgnsqrt( (Y*T(M)) * sqrt(norm) ) -> F0 (=P0)
    ns_gemm<<<640, 256, 0, stream>>>(Y, Y, M, F0, F0,
        512, (long)SLOT_USH, PLANE, 512, (long)SLOT_USH, PLANE, 512, MODE_SQ, norm, 1);

    unsigned short* Vp = F0;
    frob_part<<<512, 256, 0, stream>>>(Vp, fpart);
    frob_fin<<<1, 64, 0, stream>>>(fpart, norm2);
    fc_mfma<<<dim3(256), 256, 0, stream>>>(Vp, Wfc, part);
    fc_reduce<<<50, 256, 0, stream>>>(part, norm2, bias, out);
}

// Round 10
// 1661.804 us; speedup vs baseline: 4.7956x; 4.7956x over previous
//
#include <hip/hip_runtime.h>
#include <math.h>
#include <stdint.h>

#define DIMM 512
#define SPAT 784
#define KPAD 800
#define MATF ((size_t)DIMM * DIMM)       // 262144
#define PLANE 262144                     // hi -> lo plane offset (ushorts) for 512x512
#define SLOT_USH (2 * 262144)            // pair slot per batch (ushorts) = 1 MiB
#define XPLANE (512 * 800)
#define XSLOT (2 * 512 * 800)

typedef __attribute__((ext_vector_type(8))) short short8v;
typedef __attribute__((ext_vector_type(8))) unsigned short ushort8v;
typedef __attribute__((ext_vector_type(4))) float f32x4;

__device__ __forceinline__ unsigned short bf16_rne(float f) {
    unsigned u = __builtin_bit_cast(unsigned, f);
    u += 0x7FFFu + ((u >> 16) & 1u);
    return (unsigned short)(u >> 16);
}
__device__ __forceinline__ float bf16_to_f(unsigned short h) {
    unsigned u = ((unsigned)h) << 16;
    return __builtin_bit_cast(float, u);
}

// ---------------------------------------------------------------------------
// Pair-plane batched GEMM on SYMMETRIC outputs: only the 10 upper-triangle
// tiles of the 4x4 tile grid are computed; off-diagonal tiles mirror their
// result to the transposed position via an LDS transpose.
//   EP==0: C_pair = alpha * acc                       (Gram)
//   EP==1: C_pair = 1.5*A - 0.5*acc                   (NS: C = A @ T(M), B = M)
// hi/lo split MFMA: acc = Ah*Bh + Ah*Bl + Al*Bh  (lo*lo dropped, ~2^-17)
// 1-D grid nwg = 10 * 64 * nz (divisible by 8); XCD-aware remap (T1).
// block 256 (4 waves, 2x2 of 64x64)
// ---------------------------------------------------------------------------
template<int EP>
__global__ __launch_bounds__(256) void gemm_pair(
    const unsigned short* __restrict__ A0, const unsigned short* __restrict__ A1,
    const unsigned short* __restrict__ Bb,
    unsigned short* __restrict__ C0, unsigned short* __restrict__ C1,
    int lda, long aslot, int aplane,
    int ldb, long bslot, int bplane,
    int K, float alpha, int nz)
{
    __shared__ unsigned short sm[4 * 128 * 40];   // 40 KB; reused for transpose
    const int SM_AH = 0, SM_AL = 5120, SM_BH = 10240, SM_BL = 15360;

    // ---- XCD-aware remap: batch-contiguous per XCD
    const int nwg = gridDim.x;
    const int chunk = nwg >> 3;                   // nwg % 8 == 0
    const int bid = blockIdx.x;
    const int wu = (bid & 7) * chunk + (bid >> 3);
    const int per_batch = nz * 10;
    const int bz = wu / per_batch;
    const int rr = wu - bz * per_batch;
    const int z  = rr / 10;
    const int tile = rr - z * 10;
    int ti, tj;
    if (tile < 4)      { ti = 0; tj = tile; }
    else if (tile < 7) { ti = 1; tj = tile - 3; }
    else if (tile < 9) { ti = 2; tj = tile - 5; }
    else               { ti = 3; tj = 3; }

    const unsigned short* A  = (z ? A1 : A0) + (size_t)bz * aslot;
    const unsigned short* Bp = Bb + (size_t)bz * bslot;
    unsigned short* C = (z ? C1 : C0) + (size_t)bz * SLOT_USH;

    const int m0 = ti * 128;
    const int n0 = tj * 128;

    const int t = threadIdx.x;
    const int l = t & 63;
    const int w = t >> 6;
    const int wr = w >> 1, wc = w & 1;
    const int lr = l & 15, lc16 = (l >> 4) * 8;   // frag read: ushort offsets

    // staging: thread covers row sr (0..127), column-half sh (16 ushorts)
    const int sr = t >> 1, sh = t & 1;
    const unsigned short* pA = A  + (size_t)(m0 + sr) * lda + sh * 16;
    const unsigned short* pB = Bp + (size_t)(n0 + sr) * ldb + sh * 16;
    unsigned short* dAh = &sm[SM_AH + sr * 40 + sh * 16];
    unsigned short* dAl = &sm[SM_AL + sr * 40 + sh * 16];
    unsigned short* dBh = &sm[SM_BH + sr * 40 + sh * 16];
    unsigned short* dBl = &sm[SM_BL + sr * 40 + sh * 16];

    f32x4 acc[4][4] = {};

    ushort8v a0, a1, a2, a3, b0, b1, b2, b3;
#define LOADALL(OFF) do { \
    a0 = *(const ushort8v*)(pA + (OFF));              a1 = *(const ushort8v*)(pA + (OFF) + 8); \
    a2 = *(const ushort8v*)(pA + aplane + (OFF));     a3 = *(const ushort8v*)(pA + aplane + (OFF) + 8); \
    b0 = *(const ushort8v*)(pB + (OFF));              b1 = *(const ushort8v*)(pB + (OFF) + 8); \
    b2 = *(const ushort8v*)(pB + bplane + (OFF));     b3 = *(const ushort8v*)(pB + bplane + (OFF) + 8); \
  } while (0)

    LOADALL(0);
    const int nsteps = K >> 5;
    for (int s = 0; s < nsteps; ++s) {
        __syncthreads();
        *(ushort8v*)(dAh) = a0; *(ushort8v*)(dAh + 8) = a1;
        *(ushort8v*)(dAl) = a2; *(ushort8v*)(dAl + 8) = a3;
        *(ushort8v*)(dBh) = b0; *(ushort8v*)(dBh + 8) = b1;
        *(ushort8v*)(dBl) = b2; *(ushort8v*)(dBl + 8) = b3;
        __syncthreads();
        if (s + 1 < nsteps) LOADALL((s + 1) * 32);

        short8v ah[4], al[4], bh[4], bl[4];
#pragma unroll
        for (int f = 0; f < 4; ++f) {
            const int ra = (wr * 64 + f * 16 + lr) * 40 + lc16;
            const int rb = (wc * 64 + f * 16 + lr) * 40 + lc16;
            ah[f] = *(const short8v*)(&sm[SM_AH + ra]);
            al[f] = *(const short8v*)(&sm[SM_AL + ra]);
            bh[f] = *(const short8v*)(&sm[SM_BH + rb]);
            bl[f] = *(const short8v*)(&sm[SM_BL + rb]);
        }
#pragma unroll
        for (int fm = 0; fm < 4; ++fm)
#pragma unroll
            for (int fn = 0; fn < 4; ++fn) {
                acc[fm][fn] = __builtin_amdgcn_mfma_f32_16x16x32_bf16(ah[fm], bh[fn], acc[fm][fn], 0, 0, 0);
                acc[fm][fn] = __builtin_amdgcn_mfma_f32_16x16x32_bf16(ah[fm], bl[fn], acc[fm][fn], 0, 0, 0);
                acc[fm][fn] = __builtin_amdgcn_mfma_f32_16x16x32_bf16(al[fm], bh[fn], acc[fm][fn], 0, 0, 0);
            }
    }
#undef LOADALL

    // ---- epilogue: fold final value v into acc, write upper tile directly
    // C/D layout: col = lane&15, row = (lane>>4)*4 + reg  [m89-verified]
#pragma unroll
    for (int fm = 0; fm < 4; ++fm) {
#pragma unroll
        for (int j = 0; j < 4; ++j) {
            const int row = m0 + wr * 64 + fm * 16 + (l >> 4) * 4 + j;
            const unsigned short* arow = A + (size_t)row * lda;
            const size_t crow = (size_t)row * 512;
#pragma unroll
            for (int fn = 0; fn < 4; ++fn) {
                const int col = n0 + wc * 64 + fn * 16 + lr;
                float v = acc[fm][fn][j];
                if (EP == 0) {
                    v *= alpha;
                } else {
                    float pv = bf16_to_f(arow[col]) + bf16_to_f(arow[aplane + col]);
                    v = 1.5f * pv - 0.5f * v;
                }
                acc[fm][fn][j] = v;
                unsigned short hh = bf16_rne(v);
                C[crow + col] = hh;
                C[crow + col + PLANE] = bf16_rne(v - bf16_to_f(hh));
            }
        }
    }

    // ---- mirrored (lower-triangle) tile via LDS transpose, off-diagonal only
    if (ti != tj) {
        const int TP = 132;                       // pitch (ushorts), 8B-aligned rows
        unsigned short* smT = sm;                 // reuse (needs 128*132 <= 20480)
        const int cst = wc * 64 + lr;             // col base per lane
        const int rst = wr * 64 + (l >> 4) * 4;
        const int rc = t >> 1;                    // readout row (0..127)
        const int rh = (t & 1) * 64;              // readout col half
        __syncthreads();                          // main-loop sm reads done
#pragma unroll
        for (int pl = 0; pl < 2; ++pl) {
#pragma unroll
            for (int fm = 0; fm < 4; ++fm) {
#pragma unroll
                for (int fn = 0; fn < 4; ++fn) {
                    ushort4 q;
                    {
                        float v0 = acc[fm][fn][0], v1 = acc[fm][fn][1];
                        float v2 = acc[fm][fn][2], v3 = acc[fm][fn][3];
                        unsigned short h0 = bf16_rne(v0), h1 = bf16_rne(v1);
                        unsigned short h2 = bf16_rne(v2), h3 = bf16_rne(v3);
                        if (pl == 0) { q.x = h0; q.y = h1; q.z = h2; q.w = h3; }
                        else {
                            q.x = bf16_rne(v0 - bf16_to_f(h0));
                            q.y = bf16_rne(v1 - bf16_to_f(h1));
                            q.z = bf16_rne(v2 - bf16_to_f(h2));
                            q.w = bf16_rne(v3 - bf16_to_f(h3));
                        }
                    }
                    *(ushort4*)&smT[(cst + fn * 16) * TP + rst + fm * 16] = q;
                }
            }
            __syncthreads();
            // readout: row rc of transposed tile -> C[(n0+rc)][m0 + rh .. +63]
            {
                unsigned short* dst = C + (size_t)(n0 + rc) * 512 + m0 + rh + (pl ? PLANE : 0);
                const unsigned short* srcp = &smT[rc * TP + rh];
#pragma unroll
                for (int k = 0; k < 16; ++k)
                    *(ushort4*)(dst + k * 4) = *(const ushort4*)(srcp + k * 4);
            }
            __syncthreads();
        }
    }
}

// ---------------------------------------------------------------------------
// X (64,512,784) fp32 -> hi/lo bf16 planes, K padded to 800 with zeros
// ---------------------------------------------------------------------------
__global__ __launch_bounds__(256) void xconv(const float* __restrict__ X,
                                             unsigned short* __restrict__ XHL)
{
    const int total = 64 * 512 * 200;   // groups of 4 cols (padded width 800)
    for (int idx = blockIdx.x * 256 + threadIdx.x; idx < total; idx += gridDim.x * 256) {
        const int c4 = (idx % 200) * 4;
        const int rb = idx / 200;       // b*512 + r
        const int b = rb >> 9, r = rb & 511;
        unsigned short* dst = XHL + (size_t)b * XSLOT + (size_t)r * 800 + c4;
        ushort4 hv, lv;
        if (c4 < 784) {
            float4 x = *(const float4*)(X + (size_t)rb * 784 + c4);
            unsigned short h0 = bf16_rne(x.x), h1 = bf16_rne(x.y),
                           h2 = bf16_rne(x.z), h3 = bf16_rne(x.w);
            hv.x = h0; hv.y = h1; hv.z = h2; hv.w = h3;
            lv.x = bf16_rne(x.x - bf16_to_f(h0));
            lv.y = bf16_rne(x.y - bf16_to_f(h1));
            lv.z = bf16_rne(x.z - bf16_to_f(h2));
            lv.w = bf16_rne(x.w - bf16_to_f(h3));
        } else {
            hv.x = hv.y = hv.z = hv.w = 0;
            lv.x = lv.y = lv.z = lv.w = 0;
        }
        *(ushort4*)dst = hv;
        *(ushort4*)(dst + XPLANE) = lv;
    }
}

// ---------------------------------------------------------------------------
// Frobenius norm, two-stage: 512-block partial + 64-thread finish
// ---------------------------------------------------------------------------
__global__ __launch_bounds__(256) void frob_part(const unsigned short* __restrict__ P,
                                                 float* __restrict__ pp)
{
    const int b = blockIdx.x >> 3, sg = blockIdx.x & 7;
    const unsigned short* p = P + (size_t)b * SLOT_USH + sg * 32768;
    float s = 0.f;
    for (int i = threadIdx.x * 8; i < 32768; i += 2048) {
        ushort8v h = *(const ushort8v*)(p + i);
        ushort8v lo = *(const ushort8v*)(p + i + PLANE);
#pragma unroll
        for (int j = 0; j < 8; ++j) {
            float v = bf16_to_f(h[j]) + bf16_to_f(lo[j]);
            s += v * v;
        }
    }
    __shared__ float red[256];
    red[threadIdx.x] = s;
    __syncthreads();
    for (int wd = 128; wd > 0; wd >>= 1) {
        if (threadIdx.x < wd) red[threadIdx.x] += red[threadIdx.x + wd];
        __syncthreads();
    }
    if (threadIdx.x == 0) pp[blockIdx.x] = red[0];
}

__global__ __launch_bounds__(64) void frob_fin(const float* __restrict__ pp,
                                               float* __restrict__ out)
{
    const int b = threadIdx.x;
    float s = 0.f;
#pragma unroll
    for (int i = 0; i < 8; ++i) s += pp[b * 8 + i];
    out[b] = sqrtf(s);
}

// ---------------------------------------------------------------------------
// Y0_pair = A_pair / norm[b]
// ---------------------------------------------------------------------------
__global__ __launch_bounds__(256) void init_pair(const unsigned short* __restrict__ A,
                                                 unsigned short* __restrict__ Y,
                                                 const float* __restrict__ norm)
{
    const int total = 64 * 32768;      // groups of 8
    for (int g = blockIdx.x * 256 + threadIdx.x; g < total; g += gridDim.x * 256) {
        const int b = g >> 15;
        const int off = (g & 32767) * 8;
        const float rn = 1.0f / norm[b];
        const unsigned short* ah = A + (size_t)b * SLOT_USH + off;
        ushort8v h = *(const ushort8v*)ah;
        ushort8v lo = *(const ushort8v*)(ah + PLANE);
        ushort8v oh, ol;
#pragma unroll
        for (int j = 0; j < 8; ++j) {
            float v = (bf16_to_f(h[j]) + bf16_to_f(lo[j])) * rn;
            unsigned short hh = bf16_rne(v);
            oh[j] = hh;
            ol[j] = bf16_rne(v - bf16_to_f(hh));
        }
        unsigned short* y = Y + (size_t)b * SLOT_USH + off;
        *(ushort8v*)y = oh;
        *(ushort8v*)(y + PLANE) = ol;
    }
}

// ---------------------------------------------------------------------------
// v = sign(y*s)*sqrt(|y*s|+1e-5), s = sqrt(norm[b]); pair in -> pair out (V)
// ---------------------------------------------------------------------------
__device__ __forceinline__ float sgn_sqrt(float tv)
{
    float r = sqrtf(fabsf(tv) + 1e-5f);
    return tv > 0.f ? r : (tv < 0.f ? -r : 0.f);
}

__global__ __launch_bounds__(256) void ssqrt_pair(const unsigned short* __restrict__ Yf,
                                                  unsigned short* __restrict__ Vp,
                                                  const float* __restrict__ norm)
{
    const int total = 64 * 32768;
    for (int g = blockIdx.x * 256 + threadIdx.x; g < total; g += gridDim.x * 256) {
        const int b = g >> 15;
        const int off = (g & 32767) * 8;
        const float s = sqrtf(norm[b]);
        const unsigned short* yh = Yf + (size_t)b * SLOT_USH + off;
        ushort8v h = *(const ushort8v*)yh;
        ushort8v lo = *(const ushort8v*)(yh + PLANE);
        ushort8v oh, ol;
#pragma unroll
        for (int j = 0; j < 8; ++j) {
            float v = sgn_sqrt((bf16_to_f(h[j]) + bf16_to_f(lo[j])) * s);
            unsigned short hh = bf16_rne(v);
            oh[j] = hh;
            ol[j] = bf16_rne(v - bf16_to_f(hh));
        }
        unsigned short* vp = Vp + (size_t)b * SLOT_USH + off;
        *(ushort8v*)vp = oh;
        *(ushort8v*)(vp + PLANE) = ol;
    }
}

// ---------------------------------------------------------------------------
// FC via MFMA, k-split: grid = 128 sp x 2 nt. Per block: 64x128 output tile
// for K-chunk 2048. A = V pair (bf16 hi/lo, per-batch slots); B = W fp32
// converted to trunc-hi/lo in-register at staging. Partials fp32.
// ---------------------------------------------------------------------------
__global__ __launch_bounds__(256) void fc_mfma(
    const unsigned short* __restrict__ Vp, const float* __restrict__ Wfc,
    float* __restrict__ part)
{
    __shared__ unsigned short sm2[15360];   // AH 64x40, AL 64x40, BH 128x40, BL 128x40
    const int AH = 0, AL = 2560, BH = 5120, BL = 10240;

    const int sp = blockIdx.x >> 1;
    const int nt = blockIdx.x & 1;
    const int kbase = sp * 2048;
    const int n0 = nt * 128;

    const int t = threadIdx.x;
    const int l = t & 63;
    const int w = t >> 6;
    const int wr = w >> 1, wc = w & 1;
    const int lr = l & 15, lc16 = (l >> 4) * 8;

    const int sr = t >> 1, sh = t & 1;       // staging row / col-half
    const unsigned short* gA = Vp + (size_t)sr * SLOT_USH + kbase + sh * 16;  // t<128
    const int wrow = n0 + sr;
    const bool wv = wrow < 200;
    const float* gB = Wfc + (size_t)wrow * 262144 + kbase + sh * 16;

    unsigned short* dAh = &sm2[AH + sr * 40 + sh * 16];
    unsigned short* dAl = &sm2[AL + sr * 40 + sh * 16];
    unsigned short* dBh = &sm2[BH + sr * 40 + sh * 16];
    unsigned short* dBl = &sm2[BL + sr * 40 + sh * 16];

    f32x4 acc[2][4] = {};

    ushort8v va0, va1, vl0, vl1;
    float4 wf0, wf1, wf2, wf3;
#define FLOAD(OFF) do { \
    if (t < 128) { \
        va0 = *(const ushort8v*)(gA + (OFF));         va1 = *(const ushort8v*)(gA + (OFF) + 8); \
        vl0 = *(const ushort8v*)(gA + PLANE + (OFF)); vl1 = *(const ushort8v*)(gA + PLANE + (OFF) + 8); \
    } \
    if (wv) { \
        wf0 = *(const float4*)(gB + (OFF));      wf1 = *(const float4*)(gB + (OFF) + 4); \
        wf2 = *(const float4*)(gB + (OFF) + 8);  wf3 = *(const float4*)(gB + (OFF) + 12); \
    } else { \
        wf0 = wf1 = wf2 = wf3 = make_float4(0.f, 0.f, 0.f, 0.f); \
    } \
  } while (0)

#define WCONV(F4, Q) do { \
    ushort4 h4, l4; \
    unsigned ux = __builtin_bit_cast(unsigned, (F4).x); \
    unsigned uy = __builtin_bit_cast(unsigned, (F4).y); \
    unsigned uz = __builtin_bit_cast(unsigned, (F4).z); \
    unsigned uw = __builtin_bit_cast(unsigned, (F4).w); \
    h4.x = (unsigned short)(ux >> 16); h4.y = (unsigned short)(uy >> 16); \
    h4.z = (unsigned short)(uz >> 16); h4.w = (unsigned short)(uw >> 16); \
    l4.x = (unsigned short)(__builtin_bit_cast(unsigned, (F4).x - __builtin_bit_cast(float, ux & 0xFFFF0000u)) >> 16); \
    l4.y = (unsigned short)(__builtin_bit_cast(unsigned, (F4).y - __builtin_bit_cast(float, uy & 0xFFFF0000u)) >> 16); \
    l4.z = (unsigned short)(__builtin_bit_cast(unsigned, (F4).z - __builtin_bit_cast(float, uz & 0xFFFF0000u)) >> 16); \
    l4.w = (unsigned short)(__builtin_bit_cast(unsigned, (F4).w - __builtin_bit_cast(float, uw & 0xFFFF0000u)) >> 16); \
    *(ushort4*)(dBh + (Q) * 4) = h4; \
    *(ushort4*)(dBl + (Q) * 4) = l4; \
  } while (0)

    FLOAD(0);
    for (int s = 0; s < 64; ++s) {
        __syncthreads();
        if (t < 128) {
            *(ushort8v*)(dAh) = va0; *(ushort8v*)(dAh + 8) = va1;
            *(ushort8v*)(dAl) = vl0; *(ushort8v*)(dAl + 8) = vl1;
        }
        WCONV(wf0, 0); WCONV(wf1, 1); WCONV(wf2, 2); WCONV(wf3, 3);
        __syncthreads();
        if (s + 1 < 64) FLOAD((s + 1) * 32);

        short8v ah[2], al2[2], bh[4], bl[4];
#pragma unroll
        for (int f = 0; f < 2; ++f) {
            const int ra = (wr * 32 + f * 16 + lr) * 40 + lc16;
            ah[f]  = *(const short8v*)(&sm2[AH + ra]);
            al2[f] = *(const short8v*)(&sm2[AL + ra]);
        }
#pragma unroll
        for (int f = 0; f < 4; ++f) {
            const int rb = (wc * 64 + f * 16 + lr) * 40 + lc16;
            bh[f] = *(const short8v*)(&sm2[BH + rb]);
            bl[f] = *(const short8v*)(&sm2[BL + rb]);
        }
#pragma unroll
        for (int fm = 0; fm < 2; ++fm)
#pragma unroll
            for (int fn = 0; fn < 4; ++fn) {
                acc[fm][fn] = __builtin_amdgcn_mfma_f32_16x16x32_bf16(ah[fm],  bh[fn], acc[fm][fn], 0, 0, 0);
                acc[fm][fn] = __builtin_amdgcn_mfma_f32_16x16x32_bf16(ah[fm],  bl[fn], acc[fm][fn], 0, 0, 0);
                acc[fm][fn] = __builtin_amdgcn_mfma_f32_16x16x32_bf16(al2[fm], bh[fn], acc[fm][fn], 0, 0, 0);
            }
    }
#undef FLOAD
#undef WCONV

    float* pb = part + (size_t)(sp * 2 + nt) * 64 * 128;
#pragma unroll
    for (int fm = 0; fm < 2; ++fm)
#pragma unroll
        for (int j = 0; j < 4; ++j) {
            const int row = wr * 32 + fm * 16 + (l >> 4) * 4 + j;
#pragma unroll
            for (int fn = 0; fn < 4; ++fn) {
                const int col = wc * 64 + fn * 16 + lr;
                pb[(size_t)row * 128 + col] = acc[fm][fn][j];
            }
        }
}

// ---------------------------------------------------------------------------
// Final reduce: out[b][o] = (sum_sp part[sp][o>>7][b][o&127]) / max(n2,eps) + bias
// ---------------------------------------------------------------------------
__global__ __launch_bounds__(256) void fc_reduce(
    const float* __restrict__ part, const float* __restrict__ n2,
    const float* __restrict__ bias, float* __restrict__ out)
{
    const int p = blockIdx.x * 256 + threadIdx.x;
    if (p >= 64 * 200) return;
    const int b = p / 200, o = p % 200;
    const int nt = o >> 7, n = o & 127;
    float s = 0.f;
    for (int c = 0; c < 128; ++c)
        s += part[((size_t)(c * 2 + nt) * 64 + b) * 128 + n];
    const float nb = fmaxf(n2[b], 1e-12f);
    out[p] = s / nb + bias[o];
}

// ---------------------------------------------------------------------------
extern "C" void kernel_launch(void* const* d_in, const int* in_sizes, int n_in,
                              void* d_out, int out_size, void* d_ws, size_t ws_size,
                              hipStream_t stream)
{
    const float* X    = (const float*)d_in[0];
    const float* Wfc  = (const float*)d_in[1];
    const float* bias = (const float*)d_in[2];
    float* out = (float*)d_out;

    float* norm  = (float*)d_ws;
    float* norm2 = norm + 64;
    float* fpart = norm2 + 64;                              // 512
    float* part  = fpart + 512;                             // 8 MiB
    unsigned short* region = (unsigned short*)(part + (size_t)256 * 64 * 128);

    unsigned short* P[4];
    for (int i = 0; i < 4; ++i) P[i] = region + (size_t)i * 64 * SLOT_USH;

    unsigned short* XHL = P[2];   // 105 MB, spans P2..P3 (dead once gram done)

    // A = X X^T / 784 (MFMA hi/lo, K padded to 800), symmetric 10-tile
    xconv<<<1024, 256, 0, stream>>>(X, XHL);
    gemm_pair<0><<<dim3(10 * 64), 256, 0, stream>>>(
        XHL, XHL, XHL, P[0], P[0],
        KPAD, (long)XSLOT, XPLANE, KPAD, (long)XSLOT, XPLANE, KPAD, 1.0f / 784.0f, 1);
    frob_part<<<512, 256, 0, stream>>>(P[0], fpart);
    frob_fin<<<1, 64, 0, stream>>>(fpart, norm);
    init_pair<<<1024, 256, 0, stream>>>(P[0], P[1], norm);

    // Newton-Schulz in M-form: T(M) = (3I - M)/2 folded into epilogue
    // it0 (M0 = Y0):  Y1 = Y0*T(Y0) -> P2 ; M1 = Y1*T(Y0) -> P3
    gemm_pair<1><<<dim3(10 * 64), 256, 0, stream>>>(
        P[1], P[1], P[1], P[2], P[2],
        512, (long)SLOT_USH, PLANE, 512, (long)SLOT_USH, PLANE, 512, 1.0f, 1);
    gemm_pair<1><<<dim3(10 * 64), 256, 0, stream>>>(
        P[2], P[2], P[1], P[3], P[3],
        512, (long)SLOT_USH, PLANE, 512, (long)SLOT_USH, PLANE, 512, 1.0f, 1);

    unsigned short *Y = P[2], *M = P[3], *F0 = P[0], *F1 = P[1];
    for (int it = 1; it <= 8; ++it) {
        // s1 merged: z=0: U = M*T(M) -> F0 ; z=1: Ynew = Y*T(M) -> F1
        gemm_pair<1><<<dim3(10 * 64 * 2), 256, 0, stream>>>(
            M, Y, M, F0, F1,
            512, (long)SLOT_USH, PLANE, 512, (long)SLOT_USH, PLANE, 512, 1.0f, 2);
        // s2: Mnew = U*T(M) -> old Y slot
        gemm_pair<1><<<dim3(10 * 64), 256, 0, stream>>>(
            F0, F0, M, Y, Y,
            512, (long)SLOT_USH, PLANE, 512, (long)SLOT_USH, PLANE, 512, 1.0f, 1);
        unsigned short* Mold = M;
        M = Y;        // Mnew lives in old Y slot
        Y = F1;       // Ynew
        F1 = Mold;    // Mold freed
    }
    // it9: YF = Y*T(M) -> F0
    gemm_pair<1><<<dim3(10 * 64), 256, 0, stream>>>(
        Y, Y, M, F0, F0,
        512, (long)SLOT_USH, PLANE, 512, (long)SLOT_USH, PLANE, 512, 1.0f, 1);

    // v = signed-sqrt (pair), n2 = ||v||, FC head via MFMA k-split
    unsigned short* Vp = F1;
    ssqrt_pair<<<1024, 256, 0, stream>>>(F0, Vp, norm);
    frob_part<<<512, 256, 0, stream>>>(Vp, fpart);
    frob_fin<<<1, 64, 0, stream>>>(fpart, norm2);
    fc_mfma<<<dim3(256), 256, 0, stream>>>(Vp, Wfc, part);
    fc_reduce<<<50, 256, 0, stream>>>(part, norm2, bias, out);
}

// Round 12
// 995.759 us; speedup vs baseline: 8.0033x; 1.6689x over previous
//
#include <hip/hip_runtime.h>
#include <math.h>
#include <stdint.h>

#define DIMM 512
#define SLOT_S 262144                    // single-plane slot per batch (ushorts) = 512 KiB

typedef __attribute__((ext_vector_type(8))) _Float16 half8v;
typedef __attribute__((ext_vector_type(8))) unsigned short ushort8v;
typedef __attribute__((ext_vector_type(4))) float f32x4;

__device__ __forceinline__ unsigned short f2h(float f) {
    _Float16 h = (_Float16)f;                       // v_cvt_f16_f32 (RNE)
    return __builtin_bit_cast(unsigned short, h);
}
__device__ __forceinline__ float h2f(unsigned short u) {
    return (float)__builtin_bit_cast(_Float16, u);  // v_cvt_f32_f16
}
__device__ __forceinline__ float sgn_sqrt(float tv)
{
    float r = sqrtf(fabsf(tv) + 1e-5f);
    return tv > 0.f ? r : (tv < 0.f ? -r : 0.f);
}

// ---------------------------------------------------------------------------
// Single-fp16 NS GEMM. C = 1.5*A - 0.5*(A @ B^T-as-cols), operands fp16,
// fp32 MFMA accum. Symmetric 10-tile + TP=70 half-pass mirror (r9-validated).
// LDS: 2 planes x 128 rows x 32 ushorts, XOR-chunk involution slot =
// g ^ ((row>>1)&3) on write and read (r7/r9-validated). Rolled K-loop via
// runtime geometry. XCD-aware remap. grid 640*nz.
// ---------------------------------------------------------------------------
__global__ __launch_bounds__(256) void ns_single(
    const unsigned short* __restrict__ A0, const unsigned short* __restrict__ A1,
    const unsigned short* __restrict__ Bb,
    unsigned short* __restrict__ C0, unsigned short* __restrict__ C1,
    int lda, long aslot, int ldb, long bslot, int K, int nz)
{
    __shared__ __align__(16) unsigned short sm[8960];  // staging 8192; mirror 128*70

    const int nwg = gridDim.x;
    const int chunk = nwg >> 3;                   // nwg % 8 == 0
    const int bid = blockIdx.x;
    const int wu = (bid & 7) * chunk + (bid >> 3);
    const int per_batch = nz * 10;
    const int bz = wu / per_batch;
    const int rr = wu - bz * per_batch;
    const int z  = rr / 10;
    const int tile = rr - z * 10;
    int ti, tj;
    if (tile < 4)      { ti = 0; tj = tile; }
    else if (tile < 7) { ti = 1; tj = tile - 3; }
    else if (tile < 9) { ti = 2; tj = tile - 5; }
    else               { ti = 3; tj = 3; }

    const unsigned short* A  = (z ? A1 : A0) + (size_t)bz * aslot;
    const unsigned short* Bp = Bb + (size_t)bz * bslot;
    unsigned short* C = (z ? C1 : C0) + (size_t)bz * SLOT_S;

    const int m0 = ti * 128;
    const int n0 = tj * 128;

    const int t = threadIdx.x;
    const int l = t & 63;
    const int w = t >> 6;
    const int wr = w >> 1, wc = w & 1;
    const int lr = l & 15;
    const int sc = (((l >> 4) ^ ((l >> 1) & 3)) << 3);   // swizzled read chunk

    // staging: thread covers row sr, global chunks {2sh, 2sh+1}; XOR'd slots
    const int sr = t >> 1, sh = t & 1;
    const int swz = (sr >> 1) & 3;
    const int slot0 = ((((sh << 1) | 0) ^ swz) << 3);
    const int slot1 = ((((sh << 1) | 1) ^ swz) << 3);
    const int wbase = sr * 32;
    const unsigned short* pA = A  + (size_t)(m0 + sr) * lda + sh * 16;
    const unsigned short* pB = Bp + (size_t)(n0 + sr) * ldb + sh * 16;

    f32x4 acc[4][4] = {};

    ushort8v a0, a1, b0, b1;
#define LOADALL(OFF) do { \
    a0 = *(const ushort8v*)(pA + (OFF));  a1 = *(const ushort8v*)(pA + (OFF) + 8); \
    b0 = *(const ushort8v*)(pB + (OFF));  b1 = *(const ushort8v*)(pB + (OFF) + 8); \
  } while (0)

    LOADALL(0);
    const int nsteps = K >> 5;
    for (int s = 0; s < nsteps; ++s) {
        __syncthreads();
        *(ushort8v*)&sm[       wbase + slot0] = a0; *(ushort8v*)&sm[       wbase + slot1] = a1;
        *(ushort8v*)&sm[4096 + wbase + slot0] = b0; *(ushort8v*)&sm[4096 + wbase + slot1] = b1;
        __syncthreads();
        if (s + 1 < nsteps) LOADALL((s + 1) * 32);

        half8v ah[4], bh[4];
#pragma unroll
        for (int f = 0; f < 4; ++f) {
            const int ra = ((wr * 64 + f * 16 + lr) << 5) + sc;
            const int rb = ((wc * 64 + f * 16 + lr) << 5) + sc;
            ah[f] = *(const half8v*)(&sm[ra]);
            bh[f] = *(const half8v*)(&sm[4096 + rb]);
        }
#pragma unroll
        for (int fm = 0; fm < 4; ++fm)
#pragma unroll
            for (int fn = 0; fn < 4; ++fn)
                acc[fm][fn] = __builtin_amdgcn_mfma_f32_16x16x32_f16(ah[fm], bh[fn], acc[fm][fn], 0, 0, 0);
    }
#undef LOADALL

    // epilogue: v = 1.5*A - 0.5*acc; write upper tile
    // C/D layout: col = lane&15, row = (lane>>4)*4 + reg  [m89-verified]
#pragma unroll
    for (int fm = 0; fm < 4; ++fm) {
#pragma unroll
        for (int j = 0; j < 4; ++j) {
            const int row = m0 + wr * 64 + fm * 16 + (l >> 4) * 4 + j;
            const unsigned short* arow = A + (size_t)row * lda;
            const size_t crow = (size_t)row * 512;
#pragma unroll
            for (int fn = 0; fn < 4; ++fn) {
                const int col = n0 + wc * 64 + fn * 16 + lr;
                float v = 1.5f * h2f(arow[col]) - 0.5f * acc[fm][fn][j];
                acc[fm][fn][j] = v;
                C[crow + col] = f2h(v);
            }
        }
    }

    // mirrored (lower) tile: two 64-row half-pass LDS transposes (TP=70)
    if (ti != tj) {
        const int TP = 70;
        unsigned short* smT = sm;
        const int cst = wc * 64 + lr;
        const int r4  = (l >> 4) * 4;
        const int rc2 = t >> 1;
        const int chh = t & 1;
        __syncthreads();
#pragma unroll
        for (int h = 0; h < 2; ++h) {
            if (wr == h) {
#pragma unroll
                for (int fm = 0; fm < 4; ++fm) {
#pragma unroll
                    for (int fn = 0; fn < 4; ++fn) {
                        ushort4 q;
                        q.x = f2h(acc[fm][fn][0]);
                        q.y = f2h(acc[fm][fn][1]);
                        q.z = f2h(acc[fm][fn][2]);
                        q.w = f2h(acc[fm][fn][3]);
                        *(ushort4*)&smT[(cst + fn * 16) * TP + r4 + fm * 16] = q;
                    }
                }
            }
            __syncthreads();
            {
                unsigned short* dst = C + (size_t)(n0 + rc2) * 512 + m0 + h * 64 + chh * 32;
                const unsigned short* srcp = &smT[rc2 * TP + chh * 32];
#pragma unroll
                for (int k = 0; k < 8; ++k)
                    *(ushort4*)(dst + k * 4) = *(const ushort4*)(srcp + k * 4);
            }
            __syncthreads();
        }
    }
}

// ---------------------------------------------------------------------------
// Gram single-fp16: C = (X X^T)/784, fp32->fp16 conversion fused into staging
// (after MFMA block, overlapped). Symmetric 10-tile + mirror. K=800.
// ---------------------------------------------------------------------------
__global__ __launch_bounds__(256) void gram_single(const float* __restrict__ X,
                                                   unsigned short* __restrict__ C0,
                                                   float alpha, int K)
{
    __shared__ __align__(16) unsigned short sm[8960];

    const int nwg = gridDim.x;
    const int chunk = nwg >> 3;
    const int wu = (blockIdx.x & 7) * chunk + (blockIdx.x >> 3);
    const int bz = wu / 10, tile = wu - bz * 10;
    int ti, tj;
    if (tile < 4)      { ti = 0; tj = tile; }
    else if (tile < 7) { ti = 1; tj = tile - 3; }
    else if (tile < 9) { ti = 2; tj = tile - 5; }
    else               { ti = 3; tj = 3; }
    const int m0 = ti * 128, n0 = tj * 128;
    unsigned short* C = C0 + (size_t)bz * SLOT_S;

    const int t = threadIdx.x;
    const int l = t & 63;
    const int w = t >> 6;
    const int wr = w >> 1, wc = w & 1;
    const int lr = l & 15;
    const int sc = (((l >> 4) ^ ((l >> 1) & 3)) << 3);

    const int sr = t >> 1, sh = t & 1;
    const int swz = (sr >> 1) & 3;
    const int slot0 = ((((sh << 1) | 0) ^ swz) << 3);
    const int slot1 = ((((sh << 1) | 1) ^ swz) << 3);
    const int wbase = sr * 32;

    const float* pXa = X + ((size_t)bz * 512 + m0 + sr) * 784 + sh * 16;
    const float* pXb = X + ((size_t)bz * 512 + n0 + sr) * 784 + sh * 16;

    f32x4 acc[4][4] = {};

    float4 xa0, xa1, xa2, xa3, xb0, xb1, xb2, xb3;
    ushort8v a0, a1, b0, b1;

#define GLD(OFF) do { \
    if ((OFF) + sh * 16 < 784) { \
        xa0 = *(const float4*)(pXa + (OFF));      xa1 = *(const float4*)(pXa + (OFF) + 4); \
        xa2 = *(const float4*)(pXa + (OFF) + 8);  xa3 = *(const float4*)(pXa + (OFF) + 12); \
        xb0 = *(const float4*)(pXb + (OFF));      xb1 = *(const float4*)(pXb + (OFF) + 4); \
        xb2 = *(const float4*)(pXb + (OFF) + 8);  xb3 = *(const float4*)(pXb + (OFF) + 12); \
    } else { \
        xa0 = xa1 = xa2 = xa3 = make_float4(0.f, 0.f, 0.f, 0.f); \
        xb0 = xb1 = xb2 = xb3 = make_float4(0.f, 0.f, 0.f, 0.f); \
    } } while (0)

#define CV8(F0, F1, O) do { \
    (O)[0] = f2h((F0).x); (O)[1] = f2h((F0).y); \
    (O)[2] = f2h((F0).z); (O)[3] = f2h((F0).w); \
    (O)[4] = f2h((F1).x); (O)[5] = f2h((F1).y); \
    (O)[6] = f2h((F1).z); (O)[7] = f2h((F1).w); \
  } while (0)

#define CONVALL() do { \
    CV8(xa0, xa1, a0); CV8(xa2, xa3, a1); \
    CV8(xb0, xb1, b0); CV8(xb2, xb3, b1); \
  } while (0)

    GLD(0);
    CONVALL();
    const int nsteps = K >> 5;
    for (int s = 0; s < nsteps; ++s) {
        __syncthreads();
        *(ushort8v*)&sm[       wbase + slot0] = a0; *(ushort8v*)&sm[       wbase + slot1] = a1;
        *(ushort8v*)&sm[4096 + wbase + slot0] = b0; *(ushort8v*)&sm[4096 + wbase + slot1] = b1;
        __syncthreads();
        if (s + 1 < nsteps) GLD((s + 1) * 32);

        half8v ah[4], bh[4];
#pragma unroll
        for (int f = 0; f < 4; ++f) {
            const int ra = ((wr * 64 + f * 16 + lr) << 5) + sc;
            const int rb = ((wc * 64 + f * 16 + lr) << 5) + sc;
            ah[f] = *(const half8v*)(&sm[ra]);
            bh[f] = *(const half8v*)(&sm[4096 + rb]);
        }
#pragma unroll
        for (int fm = 0; fm < 4; ++fm)
#pragma unroll
            for (int fn = 0; fn < 4; ++fn)
                acc[fm][fn] = __builtin_amdgcn_mfma_f32_16x16x32_f16(ah[fm], bh[fn], acc[fm][fn], 0, 0, 0);
        if (s + 1 < nsteps) CONVALL();
    }
#undef GLD
#undef CV8
#undef CONVALL

#pragma unroll
    for (int fm = 0; fm < 4; ++fm) {
#pragma unroll
        for (int j = 0; j < 4; ++j) {
            const int row = m0 + wr * 64 + fm * 16 + (l >> 4) * 4 + j;
            const size_t crow = (size_t)row * 512;
#pragma unroll
            for (int fn = 0; fn < 4; ++fn) {
                const int col = n0 + wc * 64 + fn * 16 + lr;
                float v = acc[fm][fn][j] * alpha;
                acc[fm][fn][j] = v;
                C[crow + col] = f2h(v);
            }
        }
    }

    if (ti != tj) {
        const int TP = 70;
        unsigned short* smT = sm;
        const int cst = wc * 64 + lr;
        const int r4  = (l >> 4) * 4;
        const int rc2 = t >> 1;
        const int chh = t & 1;
        __syncthreads();
#pragma unroll
        for (int h = 0; h < 2; ++h) {
            if (wr == h) {
#pragma unroll
                for (int fm = 0; fm < 4; ++fm) {
#pragma unroll
                    for (int fn = 0; fn < 4; ++fn) {
                        ushort4 q;
                        q.x = f2h(acc[fm][fn][0]);
                        q.y = f2h(acc[fm][fn][1]);
                        q.z = f2h(acc[fm][fn][2]);
                        q.w = f2h(acc[fm][fn][3]);
                        *(ushort4*)&smT[(cst + fn * 16) * TP + r4 + fm * 16] = q;
                    }
                }
            }
            __syncthreads();
            {
                unsigned short* dst = C + (size_t)(n0 + rc2) * 512 + m0 + h * 64 + chh * 32;
                const unsigned short* srcp = &smT[rc2 * TP + chh * 32];
#pragma unroll
                for (int k = 0; k < 8; ++k)
                    *(ushort4*)(dst + k * 4) = *(const ushort4*)(srcp + k * 4);
            }
            __syncthreads();
        }
    }
}

// ---------------------------------------------------------------------------
// Frobenius norm (fp16 plane), two-stage: 512-block partial + finish
// ---------------------------------------------------------------------------
__global__ __launch_bounds__(256) void frob_s(const unsigned short* __restrict__ P,
                                              float* __restrict__ pp)
{
    const int b = blockIdx.x >> 3, sg = blockIdx.x & 7;
    const unsigned short* p = P + (size_t)b * SLOT_S + sg * 32768;
    float s = 0.f;
    for (int i = threadIdx.x * 8; i < 32768; i += 2048) {
        ushort8v h = *(const ushort8v*)(p + i);
#pragma unroll
        for (int j = 0; j < 8; ++j) {
            float v = h2f(h[j]);
            s += v * v;
        }
    }
    __shared__ float red[256];
    red[threadIdx.x] = s;
    __syncthreads();
    for (int wd = 128; wd > 0; wd >>= 1) {
        if (threadIdx.x < wd) red[threadIdx.x] += red[threadIdx.x + wd];
        __syncthreads();
    }
    if (threadIdx.x == 0) pp[blockIdx.x] = red[0];
}

__global__ __launch_bounds__(64) void frob_fin(const float* __restrict__ pp,
                                               float* __restrict__ out)
{
    const int b = threadIdx.x;
    float s = 0.f;
#pragma unroll
    for (int i = 0; i < 8; ++i) s += pp[b * 8 + i];
    out[b] = sqrtf(s);
}

// ---------------------------------------------------------------------------
// Y0 = f16(A / norm[b])
// ---------------------------------------------------------------------------
__global__ __launch_bounds__(256) void init_s(const unsigned short* __restrict__ A,
                                              unsigned short* __restrict__ Y,
                                              const float* __restrict__ norm)
{
    const int total = 64 * 32768;
    for (int g = blockIdx.x * 256 + threadIdx.x; g < total; g += gridDim.x * 256) {
        const int b = g >> 15;
        const int off = (g & 32767) * 8;
        const float rn = 1.0f / norm[b];
        ushort8v h = *(const ushort8v*)(A + (size_t)b * SLOT_S + off);
        ushort8v o;
#pragma unroll
        for (int j = 0; j < 8; ++j) o[j] = f2h(h2f(h[j]) * rn);
        *(ushort8v*)(Y + (size_t)b * SLOT_S + off) = o;
    }
}

// ---------------------------------------------------------------------------
// v = f16(sgn_sqrt(y * sqrt(norm[b])))
// ---------------------------------------------------------------------------
__global__ __launch_bounds__(256) void ssqrt_s(const unsigned short* __restrict__ Yf,
                                               unsigned short* __restrict__ Vp,
                                               const float* __restrict__ norm)
{
    const int total = 64 * 32768;
    for (int g = blockIdx.x * 256 + threadIdx.x; g < total; g += gridDim.x * 256) {
        const int b = g >> 15;
        const int off = (g & 32767) * 8;
        const float s = sqrtf(norm[b]);
        ushort8v h = *(const ushort8v*)(Yf + (size_t)b * SLOT_S + off);
        ushort8v o;
#pragma unroll
        for (int j = 0; j < 8; ++j) o[j] = f2h(sgn_sqrt(h2f(h[j]) * s));
        *(ushort8v*)(Vp + (size_t)b * SLOT_S + off) = o;
    }
}

// ---------------------------------------------------------------------------
// FC via MFMA (fp16), k-split: grid 256 (128 sp x 2 nt).
// A = V fp16 (64 rows); B = W fp32 -> fp16 RNE in staging. fp32 partials.
// LDS: A 64x32 @0, B 128x32 @2048; XOR-chunk involution.
// ---------------------------------------------------------------------------
__global__ __launch_bounds__(256) void fc_mfma_s(
    const unsigned short* __restrict__ Vp, const float* __restrict__ Wfc,
    float* __restrict__ part)
{
    __shared__ __align__(16) unsigned short sm2[6144];

    const int sp = blockIdx.x >> 1;
    const int nt = blockIdx.x & 1;
    const int kbase = sp * 2048;
    const int n0 = nt * 128;

    const int t = threadIdx.x;
    const int l = t & 63;
    const int w = t >> 6;
    const int wr = w >> 1, wc = w & 1;
    const int lr = l & 15;
    const int sc = (((l >> 4) ^ ((l >> 1) & 3)) << 3);

    const int sr = t >> 1, sh = t & 1;
    const int swz = (sr >> 1) & 3;
    const int slot0 = ((((sh << 1) | 0) ^ swz) << 3);
    const int slot1 = ((((sh << 1) | 1) ^ swz) << 3);

    const unsigned short* gA = Vp + (size_t)sr * SLOT_S + kbase + sh * 16;   // t<128
    const int wrow = n0 + sr;
    const bool wv = wrow < 200;
    const float* gB = Wfc + (size_t)wrow * 262144 + kbase + sh * 16;

    f32x4 acc[2][4] = {};

    ushort8v va0, va1, vb0, vb1;
    float4 wf0, wf1, wf2, wf3;
#define FLOAD(OFF) do { \
    if (t < 128) { \
        va0 = *(const ushort8v*)(gA + (OFF)); va1 = *(const ushort8v*)(gA + (OFF) + 8); \
    } \
    if (wv) { \
        wf0 = *(const float4*)(gB + (OFF));      wf1 = *(const float4*)(gB + (OFF) + 4); \
        wf2 = *(const float4*)(gB + (OFF) + 8);  wf3 = *(const float4*)(gB + (OFF) + 12); \
    } else { \
        wf0 = wf1 = wf2 = wf3 = make_float4(0.f, 0.f, 0.f, 0.f); \
    } \
    vb0[0] = f2h(wf0.x); vb0[1] = f2h(wf0.y); vb0[2] = f2h(wf0.z); vb0[3] = f2h(wf0.w); \
    vb0[4] = f2h(wf1.x); vb0[5] = f2h(wf1.y); vb0[6] = f2h(wf1.z); vb0[7] = f2h(wf1.w); \
    vb1[0] = f2h(wf2.x); vb1[1] = f2h(wf2.y); vb1[2] = f2h(wf2.z); vb1[3] = f2h(wf2.w); \
    vb1[4] = f2h(wf3.x); vb1[5] = f2h(wf3.y); vb1[6] = f2h(wf3.z); vb1[7] = f2h(wf3.w); \
  } while (0)

    FLOAD(0);
    for (int s = 0; s < 64; ++s) {
        __syncthreads();
        if (t < 128) {
            *(ushort8v*)&sm2[(sr << 5) + slot0] = va0;
            *(ushort8v*)&sm2[(sr << 5) + slot1] = va1;
        }
        *(ushort8v*)&sm2[2048 + (sr << 5) + slot0] = vb0;
        *(ushort8v*)&sm2[2048 + (sr << 5) + slot1] = vb1;
        __syncthreads();
        if (s + 1 < 64) FLOAD((s + 1) * 32);

        half8v ah[2], bh[4];
#pragma unroll
        for (int f = 0; f < 2; ++f) {
            const int ra = ((wr * 32 + f * 16 + lr) << 5) + sc;
            ah[f] = *(const half8v*)(&sm2[ra]);
        }
#pragma unroll
        for (int f = 0; f < 4; ++f) {
            const int rb = ((wc * 64 + f * 16 + lr) << 5) + sc;
            bh[f] = *(const half8v*)(&sm2[2048 + rb]);
        }
#pragma unroll
        for (int fm = 0; fm < 2; ++fm)
#pragma unroll
            for (int fn = 0; fn < 4; ++fn)
                acc[fm][fn] = __builtin_amdgcn_mfma_f32_16x16x32_f16(ah[fm], bh[fn], acc[fm][fn], 0, 0, 0);
    }
#undef FLOAD

    float* pb = part + (size_t)(sp * 2 + nt) * 64 * 128;
#pragma unroll
    for (int fm = 0; fm < 2; ++fm)
#pragma unroll
        for (int j = 0; j < 4; ++j) {
            const int row = wr * 32 + fm * 16 + (l >> 4) * 4 + j;
#pragma unroll
            for (int fn = 0; fn < 4; ++fn) {
                const int col = wc * 64 + fn * 16 + lr;
                pb[(size_t)row * 128 + col] = acc[fm][fn][j];
            }
        }
}

__global__ __launch_bounds__(256) void fc_reduce(
    const float* __restrict__ part, const float* __restrict__ n2,
    const float* __restrict__ bias, float* __restrict__ out)
{
    const int p = blockIdx.x * 256 + threadIdx.x;
    if (p >= 64 * 200) return;
    const int b = p / 200, o = p % 200;
    const int nt = o >> 7, n = o & 127;
    float s = 0.f;
    for (int c = 0; c < 128; ++c)
        s += part[((size_t)(c * 2 + nt) * 64 + b) * 128 + n];
    const float nb = fmaxf(n2[b], 1e-12f);
    out[p] = s / nb + bias[o];
}

// ---------------------------------------------------------------------------
extern "C" void kernel_launch(void* const* d_in, const int* in_sizes, int n_in,
                              void* d_out, int out_size, void* d_ws, size_t ws_size,
                              hipStream_t stream)
{
    const float* X    = (const float*)d_in[0];
    const float* Wfc  = (const float*)d_in[1];
    const float* bias = (const float*)d_in[2];
    float* out = (float*)d_out;

    float* norm  = (float*)d_ws;
    float* norm2 = norm + 64;
    float* fpart = norm2 + 64;                              // 512
    float* part  = fpart + 512;                             // 8 MiB
    unsigned short* region = (unsigned short*)(part + (size_t)256 * 64 * 128);

    unsigned short* P[4];
    for (int i = 0; i < 4; ++i) P[i] = region + (size_t)i * 64 * SLOT_S;

    // A = X X^T / 784 -> P0 (fp16); norm; Y0 = A/norm -> P1
    gram_single<<<640, 256, 0, stream>>>(X, P[0], 1.0f / 784.0f, 800);
    frob_s<<<512, 256, 0, stream>>>(P[0], fpart);
    frob_fin<<<1, 64, 0, stream>>>(fpart, norm);
    init_s<<<1024, 256, 0, stream>>>(P[0], P[1], norm);

    // Newton-Schulz in M-form: T(M) = (3I - M)/2 folded into epilogue
    // it0: Y1 = Y0*T(Y0) -> P2 ; M1 = Y1*T(Y0) -> P3
    ns_single<<<640, 256, 0, stream>>>(P[1], P[1], P[1], P[2], P[2],
        512, (long)SLOT_S, 512, (long)SLOT_S, 512, 1);
    ns_single<<<640, 256, 0, stream>>>(P[2], P[2], P[1], P[3], P[3],
        512, (long)SLOT_S, 512, (long)SLOT_S, 512, 1);

    unsigned short *Y = P[2], *M = P[3], *F0 = P[0], *F1 = P[1];
    for (int it = 1; it <= 8; ++it) {
        // s1 merged: z=0: U = M*T(M) -> F0 ; z=1: Ynew = Y*T(M) -> F1
        ns_single<<<1280, 256, 0, stream>>>(M, Y, M, F0, F1,
            512, (long)SLOT_S, 512, (long)SLOT_S, 512, 2);
        // s2: Mnew = U*T(M) -> old Y slot
        ns_single<<<640, 256, 0, stream>>>(F0, F0, M, Y, Y,
            512, (long)SLOT_S, 512, (long)SLOT_S, 512, 1);
        unsigned short* Mold = M;
        M = Y;        // Mnew lives in old Y slot
        Y = F1;       // Ynew
        F1 = Mold;    // Mold freed
    }
    // it9: YF = Y*T(M) -> F0
    ns_single<<<640, 256, 0, stream>>>(Y, Y, M, F0, F0,
        512, (long)SLOT_S, 512, (long)SLOT_S, 512, 1);

    // v = signed-sqrt, n2 = ||v||, FC head
    unsigned short* Vp = F1;
    ssqrt_s<<<1024, 256, 0, stream>>>(F0, Vp, norm);
    frob_s<<<512, 256, 0, stream>>>(Vp, fpart);
    frob_fin<<<1, 64, 0, stream>>>(fpart, norm2);
    fc_mfma_s<<<dim3(256), 256, 0, stream>>>(Vp, Wfc, part);
    fc_reduce<<<50, 256, 0, stream>>>(part, norm2, bias, out);
}

// Round 13
// 994.120 us; speedup vs baseline: 8.0165x; 1.0016x over previous
//
#include <hip/hip_runtime.h>
#include <math.h>
#include <stdint.h>

#define DIMM 512
#define SLOT_S 262144                    // single-plane slot per batch (ushorts) = 512 KiB

typedef __attribute__((ext_vector_type(8))) _Float16 half8v;
typedef __attribute__((ext_vector_type(8))) unsigned short ushort8v;
typedef __attribute__((ext_vector_type(4))) float f32x4;

__device__ __forceinline__ unsigned short f2h(float f) {
    _Float16 h = (_Float16)f;                       // v_cvt_f16_f32 (RNE)
    return __builtin_bit_cast(unsigned short, h);
}
__device__ __forceinline__ float h2f(unsigned short u) {
    return (float)__builtin_bit_cast(_Float16, u);  // v_cvt_f32_f16
}
__device__ __forceinline__ float sgn_sqrt(float tv)
{
    float r = sqrtf(fabsf(tv) + 1e-5f);
    return tv > 0.f ? r : (tv < 0.f ? -r : 0.f);
}

// ---------------------------------------------------------------------------
// fp16 NS GEMM, T-staged form: B operand is converted to T = 1.5I - 0.5*M
// IN STAGING (packed fp16 mul + diagonal insert), so acc = A@T is the final
// result directly — no epilogue A re-read (-25% traffic vs round 12).
//   mode 0: bscale=-0.5,     v = acc                (normal NS step)
//   mode 1: bscale=-0.5/n,   v = acc/n              (it0a: Y1 from raw A)
//   mode 2: bscale=-0.5/n,   v = acc                (it0b: M1, B = raw A)
//   mode 3: bscale=-0.5,     v = sgnsqrt(acc*sqrt n)(it9 + signed-sqrt fusion)
// Symmetric 10-tile + TP=70 half-pass mirror (r9-validated). LDS XOR-chunk
// involution (r7/r9-validated). Rolled K-loop (runtime geometry). XCD remap.
// ---------------------------------------------------------------------------
__global__ __launch_bounds__(256) void ns_single(
    const unsigned short* __restrict__ A0, const unsigned short* __restrict__ A1,
    const unsigned short* __restrict__ Bb,
    unsigned short* __restrict__ C0, unsigned short* __restrict__ C1,
    int lda, long aslot, int ldb, long bslot, int K,
    int mode, const float* __restrict__ norm, int nz)
{
    __shared__ __align__(16) unsigned short sm[8960];  // staging 8192; mirror 128x70

    const int nwg = gridDim.x;
    const int chunk = nwg >> 3;                   // nwg % 8 == 0
    const int bid = blockIdx.x;
    const int wu = (bid & 7) * chunk + (bid >> 3);
    const int per_batch = nz * 10;
    const int bz = wu / per_batch;
    const int rr = wu - bz * per_batch;
    const int z  = rr / 10;
    const int tile = rr - z * 10;
    int ti, tj;
    if (tile < 4)      { ti = 0; tj = tile; }
    else if (tile < 7) { ti = 1; tj = tile - 3; }
    else if (tile < 9) { ti = 2; tj = tile - 5; }
    else               { ti = 3; tj = 3; }

    const unsigned short* A  = (z ? A1 : A0) + (size_t)bz * aslot;
    const unsigned short* Bp = Bb + (size_t)bz * bslot;
    unsigned short* C = (z ? C1 : C0) + (size_t)bz * SLOT_S;

    float rn = 1.0f, sq = 0.0f;
    if (mode != 0) {
        const float nv = norm[bz];
        rn = 1.0f / nv;
        sq = sqrtf(nv);
    }
    const _Float16 bscale = (_Float16)((mode == 1 || mode == 2) ? (-0.5f * rn) : -0.5f);
    const float csc = (mode == 1) ? rn : 1.0f;

    const int m0 = ti * 128;
    const int n0 = tj * 128;

    const int t = threadIdx.x;
    const int l = t & 63;
    const int w = t >> 6;
    const int wr = w >> 1, wc = w & 1;
    const int lr = l & 15;
    const int sc = (((l >> 4) ^ ((l >> 1) & 3)) << 3);   // swizzled read chunk

    // staging: thread covers row sr, global chunks {2sh, 2sh+1}; XOR'd slots
    const int sr = t >> 1, sh = t & 1;
    const int swz = (sr >> 1) & 3;
    const int slot0 = ((((sh << 1) | 0) ^ swz) << 3);
    const int slot1 = ((((sh << 1) | 1) ^ swz) << 3);
    const int wbase = sr * 32;
    const unsigned short* pA = A  + (size_t)(m0 + sr) * lda + sh * 16;
    const unsigned short* pB = Bp + (size_t)(n0 + sr) * ldb + sh * 16;
    const int dbase = (n0 + sr) - sh * 16;        // diag index base (minus s*32)

    f32x4 acc[4][4] = {};

    ushort8v a0, a1, b0, b1;
#define LOADALL(OFF) do { \
    a0 = *(const ushort8v*)(pA + (OFF));  a1 = *(const ushort8v*)(pA + (OFF) + 8); \
    b0 = *(const ushort8v*)(pB + (OFF));  b1 = *(const ushort8v*)(pB + (OFF) + 8); \
  } while (0)

    // convert staged B chunk into T-row chunk for K-step S (diag at n0+sr)
#define CONVB(S) do { \
    half8v bv0 = __builtin_bit_cast(half8v, b0); \
    half8v bv1 = __builtin_bit_cast(half8v, b1); \
    bv0 *= bscale; bv1 *= bscale; \
    const int dj = dbase - (S) * 32; \
    _Pragma("unroll") \
    for (int j = 0; j < 8; ++j) { \
        if (dj == j)     bv0[j] += (_Float16)1.5f; \
        if (dj == j + 8) bv1[j] += (_Float16)1.5f; \
    } \
    b0 = __builtin_bit_cast(ushort8v, bv0); \
    b1 = __builtin_bit_cast(ushort8v, bv1); \
  } while (0)

    LOADALL(0);
    CONVB(0);
    const int nsteps = K >> 5;
    for (int s = 0; s < nsteps; ++s) {
        __syncthreads();
        *(ushort8v*)&sm[       wbase + slot0] = a0; *(ushort8v*)&sm[       wbase + slot1] = a1;
        *(ushort8v*)&sm[4096 + wbase + slot0] = b0; *(ushort8v*)&sm[4096 + wbase + slot1] = b1;
        __syncthreads();
        if (s + 1 < nsteps) { LOADALL((s + 1) * 32); CONVB(s + 1); }

        half8v ah[4], bh[4];
#pragma unroll
        for (int f = 0; f < 4; ++f) {
            const int ra = ((wr * 64 + f * 16 + lr) << 5) + sc;
            const int rb = ((wc * 64 + f * 16 + lr) << 5) + sc;
            ah[f] = *(const half8v*)(&sm[ra]);
            bh[f] = *(const half8v*)(&sm[4096 + rb]);
        }
#pragma unroll
        for (int fm = 0; fm < 4; ++fm)
#pragma unroll
            for (int fn = 0; fn < 4; ++fn)
                acc[fm][fn] = __builtin_amdgcn_mfma_f32_16x16x32_f16(ah[fm], bh[fn], acc[fm][fn], 0, 0, 0);
    }
#undef LOADALL
#undef CONVB

    // epilogue: v = csc*acc (+optional ssqrt); pure store, no A re-read
    // C/D layout: col = lane&15, row = (lane>>4)*4 + reg  [m89-verified]
#pragma unroll
    for (int fm = 0; fm < 4; ++fm) {
#pragma unroll
        for (int j = 0; j < 4; ++j) {
            const int row = m0 + wr * 64 + fm * 16 + (l >> 4) * 4 + j;
            const size_t crow = (size_t)row * 512;
#pragma unroll
            for (int fn = 0; fn < 4; ++fn) {
                const int col = n0 + wc * 64 + fn * 16 + lr;
                float v = csc * acc[fm][fn][j];
                if (mode == 3) v = sgn_sqrt(v * sq);
                acc[fm][fn][j] = v;
                C[crow + col] = f2h(v);
            }
        }
    }

    // mirrored (lower) tile: two 64-row half-pass LDS transposes (TP=70)
    if (ti != tj) {
        const int TP = 70;
        unsigned short* smT = sm;
        const int cst = wc * 64 + lr;
        const int r4  = (l >> 4) * 4;
        const int rc2 = t >> 1;
        const int chh = t & 1;
        __syncthreads();
#pragma unroll
        for (int h = 0; h < 2; ++h) {
            if (wr == h) {
#pragma unroll
                for (int fm = 0; fm < 4; ++fm) {
#pragma unroll
                    for (int fn = 0; fn < 4; ++fn) {
                        ushort4 q;
                        q.x = f2h(acc[fm][fn][0]);
                        q.y = f2h(acc[fm][fn][1]);
                        q.z = f2h(acc[fm][fn][2]);
                        q.w = f2h(acc[fm][fn][3]);
                        *(ushort4*)&smT[(cst + fn * 16) * TP + r4 + fm * 16] = q;
                    }
                }
            }
            __syncthreads();
            {
                unsigned short* dst = C + (size_t)(n0 + rc2) * 512 + m0 + h * 64 + chh * 32;
                const unsigned short* srcp = &smT[rc2 * TP + chh * 32];
#pragma unroll
                for (int k = 0; k < 8; ++k)
                    *(ushort4*)(dst + k * 4) = *(const ushort4*)(srcp + k * 4);
            }
            __syncthreads();
        }
    }
}

// ---------------------------------------------------------------------------
// Gram single-fp16: C = (X X^T)/784, fp32->fp16 conversion fused into staging
// (after MFMA block, overlapped). Symmetric 10-tile + mirror. K=800.
// (unchanged from round 12)
// ---------------------------------------------------------------------------
__global__ __launch_bounds__(256) void gram_single(const float* __restrict__ X,
                                                   unsigned short* __restrict__ C0,
                                                   float alpha, int K)
{
    __shared__ __align__(16) unsigned short sm[8960];

    const int nwg = gridDim.x;
    const int chunk = nwg >> 3;
    const int wu = (blockIdx.x & 7) * chunk + (blockIdx.x >> 3);
    const int bz = wu / 10, tile = wu - bz * 10;
    int ti, tj;
    if (tile < 4)      { ti = 0; tj = tile; }
    else if (tile < 7) { ti = 1; tj = tile - 3; }
    else if (tile < 9) { ti = 2; tj = tile - 5; }
    else               { ti = 3; tj = 3; }
    const int m0 = ti * 128, n0 = tj * 128;
    unsigned short* C = C0 + (size_t)bz * SLOT_S;

    const int t = threadIdx.x;
    const int l = t & 63;
    const int w = t >> 6;
    const int wr = w >> 1, wc = w & 1;
    const int lr = l & 15;
    const int sc = (((l >> 4) ^ ((l >> 1) & 3)) << 3);

    const int sr = t >> 1, sh = t & 1;
    const int swz = (sr >> 1) & 3;
    const int slot0 = ((((sh << 1) | 0) ^ swz) << 3);
    const int slot1 = ((((sh << 1) | 1) ^ swz) << 3);
    const int wbase = sr * 32;

    const float* pXa = X + ((size_t)bz * 512 + m0 + sr) * 784 + sh * 16;
    const float* pXb = X + ((size_t)bz * 512 + n0 + sr) * 784 + sh * 16;

    f32x4 acc[4][4] = {};

    float4 xa0, xa1, xa2, xa3, xb0, xb1, xb2, xb3;
    ushort8v a0, a1, b0, b1;

#define GLD(OFF) do { \
    if ((OFF) + sh * 16 < 784) { \
        xa0 = *(const float4*)(pXa + (OFF));      xa1 = *(const float4*)(pXa + (OFF) + 4); \
        xa2 = *(const float4*)(pXa + (OFF) + 8);  xa3 = *(const float4*)(pXa + (OFF) + 12); \
        xb0 = *(const float4*)(pXb + (OFF));      xb1 = *(const float4*)(pXb + (OFF) + 4); \
        xb2 = *(const float4*)(pXb + (OFF) + 8);  xb3 = *(const float4*)(pXb + (OFF) + 12); \
    } else { \
        xa0 = xa1 = xa2 = xa3 = make_float4(0.f, 0.f, 0.f, 0.f); \
        xb0 = xb1 = xb2 = xb3 = make_float4(0.f, 0.f, 0.f, 0.f); \
    } } while (0)

#define CV8(F0, F1, O) do { \
    (O)[0] = f2h((F0).x); (O)[1] = f2h((F0).y); \
    (O)[2] = f2h((F0).z); (O)[3] = f2h((F0).w); \
    (O)[4] = f2h((F1).x); (O)[5] = f2h((F1).y); \
    (O)[6] = f2h((F1).z); (O)[7] = f2h((F1).w); \
  } while (0)

#define CONVALL() do { \
    CV8(xa0, xa1, a0); CV8(xa2, xa3, a1); \
    CV8(xb0, xb1, b0); CV8(xb2, xb3, b1); \
  } while (0)

    GLD(0);
    CONVALL();
    const int nsteps = K >> 5;
    for (int s = 0; s < nsteps; ++s) {
        __syncthreads();
        *(ushort8v*)&sm[       wbase + slot0] = a0; *(ushort8v*)&sm[       wbase + slot1] = a1;
        *(ushort8v*)&sm[4096 + wbase + slot0] = b0; *(ushort8v*)&sm[4096 + wbase + slot1] = b1;
        __syncthreads();
        if (s + 1 < nsteps) GLD((s + 1) * 32);

        half8v ah[4], bh[4];
#pragma unroll
        for (int f = 0; f < 4; ++f) {
            const int ra = ((wr * 64 + f * 16 + lr) << 5) + sc;
            const int rb = ((wc * 64 + f * 16 + lr) << 5) + sc;
            ah[f] = *(const half8v*)(&sm[ra]);
            bh[f] = *(const half8v*)(&sm[4096 + rb]);
        }
#pragma unroll
        for (int fm = 0; fm < 4; ++fm)
#pragma unroll
            for (int fn = 0; fn < 4; ++fn)
                acc[fm][fn] = __builtin_amdgcn_mfma_f32_16x16x32_f16(ah[fm], bh[fn], acc[fm][fn], 0, 0, 0);
        if (s + 1 < nsteps) CONVALL();
    }
#undef GLD
#undef CV8
#undef CONVALL

#pragma unroll
    for (int fm = 0; fm < 4; ++fm) {
#pragma unroll
        for (int j = 0; j < 4; ++j) {
            const int row = m0 + wr * 64 + fm * 16 + (l >> 4) * 4 + j;
            const size_t crow = (size_t)row * 512;
#pragma unroll
            for (int fn = 0; fn < 4; ++fn) {
                const int col = n0 + wc * 64 + fn * 16 + lr;
                float v = acc[fm][fn][j] * alpha;
                acc[fm][fn][j] = v;
                C[crow + col] = f2h(v);
            }
        }
    }

    if (ti != tj) {
        const int TP = 70;
        unsigned short* smT = sm;
        const int cst = wc * 64 + lr;
        const int r4  = (l >> 4) * 4;
        const int rc2 = t >> 1;
        const int chh = t & 1;
        __syncthreads();
#pragma unroll
        for (int h = 0; h < 2; ++h) {
            if (wr == h) {
#pragma unroll
                for (int fm = 0; fm < 4; ++fm) {
#pragma unroll
                    for (int fn = 0; fn < 4; ++fn) {
                        ushort4 q;
                        q.x = f2h(acc[fm][fn][0]);
                        q.y = f2h(acc[fm][fn][1]);
                        q.z = f2h(acc[fm][fn][2]);
                        q.w = f2h(acc[fm][fn][3]);
                        *(ushort4*)&smT[(cst + fn * 16) * TP + r4 + fm * 16] = q;
                    }
                }
            }
            __syncthreads();
            {
                unsigned short* dst = C + (size_t)(n0 + rc2) * 512 + m0 + h * 64 + chh * 32;
                const unsigned short* srcp = &smT[rc2 * TP + chh * 32];
#pragma unroll
                for (int k = 0; k < 8; ++k)
                    *(ushort4*)(dst + k * 4) = *(const ushort4*)(srcp + k * 4);
            }
            __syncthreads();
        }
    }
}

// ---------------------------------------------------------------------------
// Frobenius norm (fp16 plane), two-stage: 512-block partial + finish
// ---------------------------------------------------------------------------
__global__ __launch_bounds__(256) void frob_s(const unsigned short* __restrict__ P,
                                              float* __restrict__ pp)
{
    const int b = blockIdx.x >> 3, sg = blockIdx.x & 7;
    const unsigned short* p = P + (size_t)b * SLOT_S + sg * 32768;
    float s = 0.f;
    for (int i = threadIdx.x * 8; i < 32768; i += 2048) {
        ushort8v h = *(const ushort8v*)(p + i);
#pragma unroll
        for (int j = 0; j < 8; ++j) {
            float v = h2f(h[j]);
            s += v * v;
        }
    }
    __shared__ float red[256];
    red[threadIdx.x] = s;
    __syncthreads();
    for (int wd = 128; wd > 0; wd >>= 1) {
        if (threadIdx.x < wd) red[threadIdx.x] += red[threadIdx.x + wd];
        __syncthreads();
    }
    if (threadIdx.x == 0) pp[blockIdx.x] = red[0];
}

__global__ __launch_bounds__(64) void frob_fin(const float* __restrict__ pp,
                                               float* __restrict__ out)
{
    const int b = threadIdx.x;
    float s = 0.f;
#pragma unroll
    for (int i = 0; i < 8; ++i) s += pp[b * 8 + i];
    out[b] = sqrtf(s);
}

// ---------------------------------------------------------------------------
// FC via MFMA (fp16), k-split: grid 256 (128 sp x 2 nt). (unchanged)
// ---------------------------------------------------------------------------
__global__ __launch_bounds__(256) void fc_mfma_s(
    const unsigned short* __restrict__ Vp, const float* __restrict__ Wfc,
    float* __restrict__ part)
{
    __shared__ __align__(16) unsigned short sm2[6144];

    const int sp = blockIdx.x >> 1;
    const int nt = blockIdx.x & 1;
    const int kbase = sp * 2048;
    const int n0 = nt * 128;

    const int t = threadIdx.x;
    const int l = t & 63;
    const int w = t >> 6;
    const int wr = w >> 1, wc = w & 1;
    const int lr = l & 15;
    const int sc = (((l >> 4) ^ ((l >> 1) & 3)) << 3);

    const int sr = t >> 1, sh = t & 1;
    const int swz = (sr >> 1) & 3;
    const int slot0 = ((((sh << 1) | 0) ^ swz) << 3);
    const int slot1 = ((((sh << 1) | 1) ^ swz) << 3);

    const unsigned short* gA = Vp + (size_t)sr * SLOT_S + kbase + sh * 16;   // t<128
    const int wrow = n0 + sr;
    const bool wv = wrow < 200;
    const float* gB = Wfc + (size_t)wrow * 262144 + kbase + sh * 16;

    f32x4 acc[2][4] = {};

    ushort8v va0, va1, vb0, vb1;
    float4 wf0, wf1, wf2, wf3;
#define FLOAD(OFF) do { \
    if (t < 128) { \
        va0 = *(const ushort8v*)(gA + (OFF)); va1 = *(const ushort8v*)(gA + (OFF) + 8); \
    } \
    if (wv) { \
        wf0 = *(const float4*)(gB + (OFF));      wf1 = *(const float4*)(gB + (OFF) + 4); \
        wf2 = *(const float4*)(gB + (OFF) + 8);  wf3 = *(const float4*)(gB + (OFF) + 12); \
    } else { \
        wf0 = wf1 = wf2 = wf3 = make_float4(0.f, 0.f, 0.f, 0.f); \
    } \
    vb0[0] = f2h(wf0.x); vb0[1] = f2h(wf0.y); vb0[2] = f2h(wf0.z); vb0[3] = f2h(wf0.w); \
    vb0[4] = f2h(wf1.x); vb0[5] = f2h(wf1.y); vb0[6] = f2h(wf1.z); vb0[7] = f2h(wf1.w); \
    vb1[0] = f2h(wf2.x); vb1[1] = f2h(wf2.y); vb1[2] = f2h(wf2.z); vb1[3] = f2h(wf2.w); \
    vb1[4] = f2h(wf3.x); vb1[5] = f2h(wf3.y); vb1[6] = f2h(wf3.z); vb1[7] = f2h(wf3.w); \
  } while (0)

    FLOAD(0);
    for (int s = 0; s < 64; ++s) {
        __syncthreads();
        if (t < 128) {
            *(ushort8v*)&sm2[(sr << 5) + slot0] = va0;
            *(ushort8v*)&sm2[(sr << 5) + slot1] = va1;
        }
        *(ushort8v*)&sm2[2048 + (sr << 5) + slot0] = vb0;
        *(ushort8v*)&sm2[2048 + (sr << 5) + slot1] = vb1;
        __syncthreads();
        if (s + 1 < 64) FLOAD((s + 1) * 32);

        half8v ah[2], bh[4];
#pragma unroll
        for (int f = 0; f < 2; ++f) {
            const int ra = ((wr * 32 + f * 16 + lr) << 5) + sc;
            ah[f] = *(const half8v*)(&sm2[ra]);
        }
#pragma unroll
        for (int f = 0; f < 4; ++f) {
            const int rb = ((wc * 64 + f * 16 + lr) << 5) + sc;
            bh[f] = *(const half8v*)(&sm2[2048 + rb]);
        }
#pragma unroll
        for (int fm = 0; fm < 2; ++fm)
#pragma unroll
            for (int fn = 0; fn < 4; ++fn)
                acc[fm][fn] = __builtin_amdgcn_mfma_f32_16x16x32_f16(ah[fm], bh[fn], acc[fm][fn], 0, 0, 0);
    }
#undef FLOAD

    float* pb = part + (size_t)(sp * 2 + nt) * 64 * 128;
#pragma unroll
    for (int fm = 0; fm < 2; ++fm)
#pragma unroll
        for (int j = 0; j < 4; ++j) {
            const int row = wr * 32 + fm * 16 + (l >> 4) * 4 + j;
#pragma unroll
            for (int fn = 0; fn < 4; ++fn) {
                const int col = wc * 64 + fn * 16 + lr;
                pb[(size_t)row * 128 + col] = acc[fm][fn][j];
            }
        }
}

__global__ __launch_bounds__(256) void fc_reduce(
    const float* __restrict__ part, const float* __restrict__ n2,
    const float* __restrict__ bias, float* __restrict__ out)
{
    const int p = blockIdx.x * 256 + threadIdx.x;
    if (p >= 64 * 200) return;
    const int b = p / 200, o = p % 200;
    const int nt = o >> 7, n = o & 127;
    float s = 0.f;
    for (int c = 0; c < 128; ++c)
        s += part[((size_t)(c * 2 + nt) * 64 + b) * 128 + n];
    const float nb = fmaxf(n2[b], 1e-12f);
    out[p] = s / nb + bias[o];
}

// ---------------------------------------------------------------------------
extern "C" void kernel_launch(void* const* d_in, const int* in_sizes, int n_in,
                              void* d_out, int out_size, void* d_ws, size_t ws_size,
                              hipStream_t stream)
{
    const float* X    = (const float*)d_in[0];
    const float* Wfc  = (const float*)d_in[1];
    const float* bias = (const float*)d_in[2];
    float* out = (float*)d_out;

    float* norm  = (float*)d_ws;
    float* norm2 = norm + 64;
    float* fpart = norm2 + 64;                              // 512
    float* part  = fpart + 512;                             // 8 MiB
    unsigned short* region = (unsigned short*)(part + (size_t)256 * 64 * 128);

    unsigned short* P[4];
    for (int i = 0; i < 4; ++i) P[i] = region + (size_t)i * 64 * SLOT_S;

    // A = X X^T / 784 -> P0 (fp16); norm
    gram_single<<<640, 256, 0, stream>>>(X, P[0], 1.0f / 784.0f, 800);
    frob_s<<<512, 256, 0, stream>>>(P[0], fpart);
    frob_fin<<<1, 64, 0, stream>>>(fpart, norm);

    // NS in T-staged M-form. No init pass: it0 works directly on raw A.
    // it0a (mode 1): Y1 = (A/n)*T0, T0 staged from raw A with bscale=-0.5/n
    ns_single<<<640, 256, 0, stream>>>(P[0], P[0], P[0], P[2], P[2],
        512, (long)SLOT_S, 512, (long)SLOT_S, 512, 1, norm, 1);
    // it0b (mode 2): M1 = Y1*T0
    ns_single<<<640, 256, 0, stream>>>(P[2], P[2], P[0], P[3], P[3],
        512, (long)SLOT_S, 512, (long)SLOT_S, 512, 2, norm, 1);

    unsigned short *Y = P[2], *M = P[3], *F0 = P[0], *F1 = P[1];
    for (int it = 1; it <= 8; ++it) {
        // s1 merged: z=0: U = M*T(M) -> F0 ; z=1: Ynew = Y*T(M) -> F1
        ns_single<<<1280, 256, 0, stream>>>(M, Y, M, F0, F1,
            512, (long)SLOT_S, 512, (long)SLOT_S, 512, 0, norm, 2);
        // s2: Mnew = U*T(M) -> old Y slot
        ns_single<<<640, 256, 0, stream>>>(F0, F0, M, Y, Y,
            512, (long)SLOT_S, 512, (long)SLOT_S, 512, 0, norm, 1);
        unsigned short* Mold = M;
        M = Y;        // Mnew lives in old Y slot
        Y = F1;       // Ynew
        F1 = Mold;    // Mold freed
    }
    // it9 (mode 3): V = sgnsqrt( (Y*T(M)) * sqrt(n) ) -> F0
    ns_single<<<640, 256, 0, stream>>>(Y, Y, M, F0, F0,
        512, (long)SLOT_S, 512, (long)SLOT_S, 512, 3, norm, 1);

    // n2 = ||V||; FC head
    unsigned short* Vp = F0;
    frob_s<<<512, 256, 0, stream>>>(Vp, fpart);
    frob_fin<<<1, 64, 0, stream>>>(fpart, norm2);
    fc_mfma_s<<<dim3(256), 256, 0, stream>>>(Vp, Wfc, part);
    fc_reduce<<<50, 256, 0, stream>>>(part, norm2, bias, out);
}